// Round 5
// baseline (7462.456 us; speedup 1.0000x reference)
//
#include <hip/hip_runtime.h>
#include <stdint.h>
#include <math.h>

// ============================================================================
// MCFNet on MI355X (gfx950).  INPUTS FLOAT32; OUTPUT FLOAT32.
// Numerics: all tensors stored f32.  Every matmul runs on MFMA bf16 with
// 3-plane splits (x = h + m + l, rep error ~2^-27) and 6 passes
// (hh, hm, mh, hl, lh, mm).  Weights pre-split into 3 transposed bf16 planes.
//
// R5 (attn-only change on the R4 skeleton; everything else byte-identical):
//  - attn phase 1: sched_barrier REMOVED -> compiler interleaves the 8
//    independent MFMA chains and software-pipelines the K loads (R4's
//    pinning serialized each tile's 6 dependent MFMAs).
//  - attn phase 3 (hd=768): 4 simultaneous nt-accumulators per wave sharing
//    one P-fragment load -> 4-way MFMA ILP, 4x fewer LDS P reads.
//  - attn phase 2: interleaved column ownership (col = c16 + 16*c) -> LDS
//    bank aliasing drops 16-way -> 2-way (free).  Row max identical (fmax
//    assoc); softmax sum grouping differs by ~1 ulp (accepted).
//  - gemm_k / host schedule untouched (proven at the 2-barrier structural
//    ceiling; becomes next target once visible in top-5).
// ============================================================================

typedef unsigned short USH;
typedef __attribute__((ext_vector_type(8))) short short8;
typedef __attribute__((ext_vector_type(4))) float floatx4;

#define MFMA16(a, b, c) __builtin_amdgcn_mfma_f32_16x16x32_bf16((a), (b), (c), 0, 0, 0)

static constexpr int NB = 32;          // batch
static constexpr int SS = 512;         // seq len
static constexpr int DD = 768;         // model dim
static constexpr int MM = NB * SS;     // 16384 rows

__device__ __forceinline__ float bf2f(USH h) {
    return __uint_as_float(((unsigned)h) << 16);
}
__device__ __forceinline__ USH f2bf(float x) {          // round-to-nearest-even
    unsigned u = __float_as_uint(x);
    return (USH)((u + 0x7fffu + ((u >> 16) & 1u)) >> 16);
}
// 3-plane split: x = h + m + l + err, |err| <= 2^-27 |x| (residuals exact).
__device__ __forceinline__ void split3(float x, USH &h, USH &m, USH &l) {
    h = f2bf(x);
    const float r1 = x - bf2f(h);
    m = f2bf(r1);
    const float r2 = r1 - bf2f(m);
    l = f2bf(r2);
}
__device__ __forceinline__ void split3x8(const float* v, short8 &H, short8 &M, short8 &L) {
#pragma unroll
    for (int j = 0; j < 8; ++j) {
        USH h, m, l;
        split3(v[j], h, m, l);
        H[j] = (short)h; M[j] = (short)m; L[j] = (short)l;
    }
}
__device__ __forceinline__ uint2 pk4(USH a, USH b, USH c, USH d) {
    uint2 r;
    r.x = (unsigned)a | ((unsigned)b << 16);
    r.y = (unsigned)c | ((unsigned)d << 16);
    return r;
}

// ---------------------------------------------------------------------------
// Weight transpose+split: f32 [R][768] -> 3 bf16 planes [768][R].
// ---------------------------------------------------------------------------
struct TransArgs {
    const float* in[13];
    USH* o0[13]; USH* o1[13]; USH* o2[13];
    int R[13];
};

__global__ __launch_bounds__(256) void trans_k(TransArgs a) {
    const int mi = blockIdx.z;
    const float* __restrict__ in = a.in[mi];
    USH* __restrict__ o0 = a.o0[mi];
    USH* __restrict__ o1 = a.o1[mi];
    USH* __restrict__ o2 = a.o2[mi];
    const int R = a.R[mi];
    const int bx = blockIdx.x, by = blockIdx.y;
    if (bx * 32 >= R) return;
    __shared__ float t[32][33];
    const int tx = threadIdx.x & 31, ty = threadIdx.x >> 5;   // 32 x 8
#pragma unroll
    for (int i = 0; i < 4; ++i)
        t[ty + i * 8][tx] = in[(size_t)(bx * 32 + ty + i * 8) * 768 + by * 32 + tx];
    __syncthreads();
#pragma unroll
    for (int i = 0; i < 4; ++i) {
        USH h, m, l;
        split3(t[tx][ty + i * 8], h, m, l);
        const size_t o = (size_t)(by * 32 + ty + i * 8) * R + bx * 32 + tx;
        o0[o] = h; o1[o] = m; o2[o] = l;
    }
}

// ---------------------------------------------------------------------------
// Embedding gather: dst[m,:] = table[ids[m],:]  (f32 copy)
// ---------------------------------------------------------------------------
__global__ __launch_bounds__(256) void gather_k(const int* __restrict__ ids,
                                                const float* __restrict__ table,
                                                float* __restrict__ dst) {
    const int g  = blockIdx.x * 256 + threadIdx.x;
    const int m  = g / 192;
    const int c4 = (g - m * 192) * 4;
    const int id = ids[m];
    *(float4*)(dst + (size_t)m * DD + c4) =
        *(const float4*)(table + (size_t)id * DD + c4);
}

// ---------------------------------------------------------------------------
// RoPE cos/sin table: tab[s][i] = {cos,sin}(s * theta_i), 512 x 384.
// Bit-identical math to rope_k's per-thread computation.
// ---------------------------------------------------------------------------
__global__ __launch_bounds__(256) void tab_k(float* __restrict__ tab) {
    const int p = blockIdx.x * 256 + threadIdx.x;
    const int s = p / 384;
    const int i = p - s * 384;
    const float ef = (-2.0f * (float)i) / 768.0f;
    const float th = (float)pow(10000.0, (double)ef);
    const float ang = (float)s * th;
    float sn, cs;
    sincosf(ang, &sn, &cs);
    tab[2 * p]     = cs;
    tab[2 * p + 1] = sn;
}

// Slow-path RoPE (R0, pow per thread), in-place f32.
__global__ __launch_bounds__(256) void rope_k(float* __restrict__ X) {
    const int p = blockIdx.x * 256 + threadIdx.x;
    const int m = p / 384;
    const int i = p - m * 384;
    const int s = m & (SS - 1);
    const float ef = (-2.0f * (float)i) / 768.0f;
    const float th = (float)pow(10000.0, (double)ef);
    const float ang = (float)s * th;
    float sn, cs;
    sincosf(ang, &sn, &cs);
    float2 x = *(float2*)(X + (size_t)m * DD + 2 * i);
    float2 y;
    y.x = x.x * cs - x.y * sn;
    y.y = x.y * cs + x.x * sn;
    *(float2*)(X + (size_t)m * DD + 2 * i) = y;
}

// ---------------------------------------------------------------------------
// GEMM: C[Mc,768] = A[Mc,K] @ W[K,768] + bias.   A f32 (A1 = k>=768 half of
// the K=1536 concat).  W pre-split 3 bf16 planes [768][K] (ldb).  6 MFMA
// passes, in-kernel A split3 (R0 structure — measured at ceiling).
// act: 0 none, 1 SiLU.
// tout: 0 f32 row-major; 1 TRANSPOSED 3-plane bf16 (V^T) via LDS-coalesced
//       stores; 2 transposed f32 (slow path V^T); 3 row-major 3-plane bf16
//       (K planes).
// rope: 1 -> apply interleaved RoPE in epilogue (pair via __shfl_xor(x,1),
//       cos/sin from tab).  Only with act=0, tout 0 or 3.
// XCD-chunked bijective block swizzle (applies when grid %8 == 0).
// ---------------------------------------------------------------------------
__global__ __launch_bounds__(256) void gemm_k(
    const float* __restrict__ A0, const float* __restrict__ A1,
    const USH* __restrict__ B0, const USH* __restrict__ B1, const USH* __restrict__ B2,
    int ldb, const float* __restrict__ bias,
    float* __restrict__ C, USH* __restrict__ S0p, USH* __restrict__ S1p,
    USH* __restrict__ S2p, const float* __restrict__ tab,
    int K, int act, int tout, int rope, int Mc)
{
    __shared__ __align__(16) USH smem[24576];
    USH* const sA0 = smem;
    USH* const sA1 = smem + 4096;
    USH* const sA2 = smem + 8192;
    USH* const sB0 = smem + 12288;
    USH* const sB1 = smem + 16384;
    USH* const sB2 = smem + 20480;

    const int tid  = threadIdx.x;
    const int lane = tid & 63;
    const int w    = tid >> 6;
    const int quad = lane >> 4, l15 = lane & 15;
    const int wm = (w >> 1) * 64, wn = (w & 1) * 64;

    // XCD-chunked bijective swizzle: consecutive work-ids share an XCD's L2.
    const int nbx = gridDim.x;
    const int tot = nbx * (int)gridDim.y;
    int bid = blockIdx.y * nbx + blockIdx.x;
    if ((tot & 7) == 0) bid = (bid & 7) * (tot >> 3) + (bid >> 3);
    const int byy = bid / nbx;
    const int gm0 = (bid - byy * nbx) * 128, gn0 = byy * 128;

    const int i0 = tid * 2, i1 = tid * 2 + 1;
    const int r0 = i0 >> 2, c0 = (i0 & 3) << 3;
    const int r1 = i1 >> 2, c1 = (i1 & 3) << 3;

    const floatx4 zero = {0.f, 0.f, 0.f, 0.f};
    floatx4 acc[4][4];
#pragma unroll
    for (int i = 0; i < 4; ++i)
#pragma unroll
        for (int j = 0; j < 4; ++j) acc[i][j] = zero;

    for (int k0 = 0; k0 < K; k0 += 32) {
        const float* __restrict__ A = (k0 < 768) ? A0 : A1;
        const int kof = (k0 < 768) ? k0 : (k0 - 768);

        // ---- B staging: 3 pre-split planes, 2 uint4 per plane per thread ----
        *(uint4*)&sB0[r0 * 32 + c0] = *(const uint4*)(B0 + (size_t)(gn0 + r0) * ldb + k0 + c0);
        *(uint4*)&sB0[r1 * 32 + c1] = *(const uint4*)(B0 + (size_t)(gn0 + r1) * ldb + k0 + c1);
        *(uint4*)&sB1[r0 * 32 + c0] = *(const uint4*)(B1 + (size_t)(gn0 + r0) * ldb + k0 + c0);
        *(uint4*)&sB1[r1 * 32 + c1] = *(const uint4*)(B1 + (size_t)(gn0 + r1) * ldb + k0 + c1);
        *(uint4*)&sB2[r0 * 32 + c0] = *(const uint4*)(B2 + (size_t)(gn0 + r0) * ldb + k0 + c0);
        *(uint4*)&sB2[r1 * 32 + c1] = *(const uint4*)(B2 + (size_t)(gn0 + r1) * ldb + k0 + c1);

        // ---- A staging: f32 -> split3 -> 3 planes; 4 float4 per thread ----
#pragma unroll
        for (int u = 0; u < 4; ++u) {
            const int idx = tid + u * 256;           // [0,1024)
            const int r = idx >> 3, c = (idx & 7) * 4;
            const float4 v = *(const float4*)(A + (size_t)(gm0 + r) * 768 + kof + c);
            USH h[4], m[4], l[4];
            split3(v.x, h[0], m[0], l[0]);
            split3(v.y, h[1], m[1], l[1]);
            split3(v.z, h[2], m[2], l[2]);
            split3(v.w, h[3], m[3], l[3]);
            *(uint2*)&sA0[r * 32 + c] = pk4(h[0], h[1], h[2], h[3]);
            *(uint2*)&sA1[r * 32 + c] = pk4(m[0], m[1], m[2], m[3]);
            *(uint2*)&sA2[r * 32 + c] = pk4(l[0], l[1], l[2], l[3]);
        }
        __syncthreads();

        short8 a0[4], a1f[4], a2[4], b0[4], b1f[4], b2[4];
#pragma unroll
        for (int t = 0; t < 4; ++t) {
            const int ao = (wm + t * 16 + l15) * 32 + quad * 8;
            const int bo = (wn + t * 16 + l15) * 32 + quad * 8;
            a0[t]  = *(const short8*)&sA0[ao];
            a1f[t] = *(const short8*)&sA1[ao];
            a2[t]  = *(const short8*)&sA2[ao];
            b0[t]  = *(const short8*)&sB0[bo];
            b1f[t] = *(const short8*)&sB1[bo];
            b2[t]  = *(const short8*)&sB2[bo];
        }
        // 6 passes: hh, hm, mh, hl, lh, mm
#pragma unroll
        for (int i = 0; i < 4; ++i)
#pragma unroll
            for (int j = 0; j < 4; ++j) acc[i][j] = MFMA16(a0[i],  b0[j],  acc[i][j]);
#pragma unroll
        for (int i = 0; i < 4; ++i)
#pragma unroll
            for (int j = 0; j < 4; ++j) acc[i][j] = MFMA16(a0[i],  b1f[j], acc[i][j]);
#pragma unroll
        for (int i = 0; i < 4; ++i)
#pragma unroll
            for (int j = 0; j < 4; ++j) acc[i][j] = MFMA16(a1f[i], b0[j],  acc[i][j]);
#pragma unroll
        for (int i = 0; i < 4; ++i)
#pragma unroll
            for (int j = 0; j < 4; ++j) acc[i][j] = MFMA16(a0[i],  b2[j],  acc[i][j]);
#pragma unroll
        for (int i = 0; i < 4; ++i)
#pragma unroll
            for (int j = 0; j < 4; ++j) acc[i][j] = MFMA16(a2[i],  b0[j],  acc[i][j]);
#pragma unroll
        for (int i = 0; i < 4; ++i)
#pragma unroll
            for (int j = 0; j < 4; ++j) acc[i][j] = MFMA16(a1f[i], b1f[j], acc[i][j]);
        __syncthreads();
    }

    // ---- epilogue ----
    if (tout == 1) {
        // V^T planes via LDS transpose -> coalesced short8 stores.
        // sT stride 144 USH (288B: 16B-aligned rows, banks spread).
        USH* const sT = smem;                       // 128*144 = 18432 USH
#pragma unroll
        for (int p = 0; p < 3; ++p) {
            __syncthreads();
#pragma unroll
            for (int j = 0; j < 4; ++j) {
                const int col = gn0 + wn + j * 16 + l15;
                const int cl  = wn + j * 16 + l15;
                const float bv = bias ? bias[col] : 0.0f;
#pragma unroll
                for (int i = 0; i < 4; ++i) {
#pragma unroll
                    for (int r = 0; r < 4; ++r) {
                        const int rl = wm + i * 16 + quad * 4 + r;
                        USH h, m, l;
                        split3(acc[i][j][r] + bv, h, m, l);
                        sT[cl * 144 + rl] = (p == 0) ? h : ((p == 1) ? m : l);
                    }
                }
            }
            __syncthreads();
            USH* const dst = (p == 0) ? S0p : ((p == 1) ? S1p : S2p);
#pragma unroll
            for (int u = 0; u < 8; ++u) {
                const int cc = u * 256 + tid;       // [0, 2048)
                const int cl = cc >> 4, off = (cc & 15) * 8;
                *(short8*)(dst + (size_t)(gn0 + cl) * Mc + gm0 + off) =
                    *(const short8*)&sT[cl * 144 + off];
            }
        }
        return;
    }

#pragma unroll
    for (int j = 0; j < 4; ++j) {
        const int col = gn0 + wn + j * 16 + l15;
        const float bv = bias ? bias[col] : 0.0f;
#pragma unroll
        for (int i = 0; i < 4; ++i) {
#pragma unroll
            for (int r = 0; r < 4; ++r) {
                const int row = gm0 + wm + i * 16 + quad * 4 + r;
                float x = acc[i][j][r] + bv;
                if (act == 1) {
                    const float s = 1.0f / (1.0f + expf(-x));   // sigmoid then mul
                    x = x * s;
                }
                if (rope) {
                    // partner lane holds col^1, same row; same math as rope_k.
                    const float px = __shfl_xor(x, 1, 64);
                    const float2 t = *(const float2*)(tab +
                        2 * ((row & (SS - 1)) * 384 + (col >> 1)));
                    x = (col & 1) ? (x * t.x + px * t.y)
                                  : (x * t.x - px * t.y);
                }
                if (tout == 3) {
                    USH h, m, l;
                    split3(x, h, m, l);
                    const size_t o = (size_t)row * 768 + col;
                    S0p[o] = h; S1p[o] = m; S2p[o] = l;
                } else if (tout == 2) {
                    C[(size_t)col * Mc + row] = x;
                } else {
                    C[(size_t)row * 768 + col] = x;
                }
            }
        }
    }
}

// ---------------------------------------------------------------------------
// FAST fused attention (R5).  Q f32 (split on the fly, once per block),
// K planes [Mc][768], V planes transposed [768][Mc].
// Phase 1: free-scheduled loads + 8 independent MFMA chains (no barriers).
// Phase 2: interleaved column ownership (2-way LDS bank aliasing, free).
// Phase 3: hd=768 -> 4 simultaneous nt-accumulators sharing one P fragment.
// XCD-chunked bijective block swizzle.  grid: (SS/16, chB*H), block 256.
// O may alias Q (per-block row ownership).
// ---------------------------------------------------------------------------
__global__ __launch_bounds__(256) void attn_fast_k(
    const float* __restrict__ Q,
    const USH* __restrict__ KH, const USH* __restrict__ KM, const USH* __restrict__ KL,
    const USH* __restrict__ VH, const USH* __restrict__ VM, const USH* __restrict__ VL,
    float* __restrict__ O, int H, int hd, int Mc)
{
    __shared__ __align__(16) float S[16][520];      // scores; later P0|P1 overlay
    __shared__ __align__(16) USH P2buf[16 * 520];   // P lo plane
    __shared__ float red[16][16];
    __shared__ float stat[16];

    const int tid  = threadIdx.x;
    const int lane = tid & 63;
    const int w    = tid >> 6;
    const int quad = lane >> 4, l15 = lane & 15;

    // XCD-chunked bijective swizzle: same-(b,h) blocks share one XCD's L2.
    const int nbx = gridDim.x;                      // SS/16 = 32
    const int tot = nbx * (int)gridDim.y;
    int bid = blockIdx.y * nbx + blockIdx.x;
    if ((tot & 7) == 0) bid = (bid & 7) * (tot >> 3) + (bid >> 3);
    const int yy = bid / nbx;
    const int q0 = (bid - yy * nbx) * 16;
    const int b = yy / H;
    const int h = yy - b * H;

    const floatx4 zero = {0.f, 0.f, 0.f, 0.f};

    // ---- phase 1: scores.  wave w covers keys [w*128, w*128+128) ----
    floatx4 acc[8];
#pragma unroll
    for (int t = 0; t < 8; ++t) acc[t] = zero;

    const size_t qbase  = ((size_t)(b * SS + q0 + l15)) * DD + h * hd;
    const size_t kstrip = ((size_t)(b * SS + w * 128 + l15)) * DD + h * hd;
    const int nks = hd >> 5;
    for (int ks = 0; ks < nks; ++ks) {
        const int co = ks * 32 + quad * 8;
        float qv[8];
        *(float4*)&qv[0] = *(const float4*)(Q + qbase + co);
        *(float4*)&qv[4] = *(const float4*)(Q + qbase + co + 4);
        short8 qh, qm, ql;
        split3x8(qv, qh, qm, ql);
#pragma unroll
        for (int t = 0; t < 8; ++t) {
            const size_t kb = kstrip + (size_t)t * 16 * DD + co;
            const short8 kh = *(const short8*)&KH[kb];
            const short8 km = *(const short8*)&KM[kb];
            const short8 kl = *(const short8*)&KL[kb];
            acc[t] = MFMA16(qh, kh, acc[t]);
            acc[t] = MFMA16(qh, km, acc[t]);
            acc[t] = MFMA16(qm, kh, acc[t]);
            acc[t] = MFMA16(qh, kl, acc[t]);
            acc[t] = MFMA16(ql, kh, acc[t]);
            acc[t] = MFMA16(qm, km, acc[t]);
        }
    }
#pragma unroll
    for (int t = 0; t < 8; ++t)
#pragma unroll
        for (int r = 0; r < 4; ++r)
            S[quad * 4 + r][w * 128 + t * 16 + l15] = acc[t][r] * 8.0f;
    __syncthreads();

    // ---- phase 2: softmax.  16 threads/row; thread c16 owns cols c16+16c
    // (interleaved -> 2-way LDS bank aliasing instead of 16-way). ----
    const int row = tid >> 4, c16 = tid & 15;
    float mx = -3.4e38f;
#pragma unroll 8
    for (int c = 0; c < 32; ++c) mx = fmaxf(mx, S[row][c16 + 16 * c]);
    red[row][c16] = mx;
    __syncthreads();
    if (c16 == 0) {
        float m2 = red[row][0];
#pragma unroll
        for (int j = 1; j < 16; ++j) m2 = fmaxf(m2, red[row][j]);
        stat[row] = m2;
    }
    __syncthreads();
    mx = stat[row];
    float ev[32];
    float sum = 0.f;
#pragma unroll 8
    for (int c = 0; c < 32; ++c) {
        ev[c] = expf(S[row][c16 + 16 * c] - mx);
        sum += ev[c];
    }
    red[row][c16] = sum;
    __syncthreads();
    if (c16 == 0) {
        float s2 = 0.f;
#pragma unroll
        for (int j = 0; j < 16; ++j) s2 += red[row][j];
        stat[row] = s2;
    }
    __syncthreads();                       // all S reads done -> overlay P
    const float den = stat[row];
    USH* const P0 = (USH*)&S[0][0];        // P hi plane
    USH* const P1 = P0 + 16 * 520;         // P mid plane
    USH* const P2 = P2buf;                 // P lo plane
#pragma unroll 8
    for (int c = 0; c < 32; ++c) {
        const float pr = ev[c] / den;      // divide, like numpy softmax
        USH hh, mm, ll;
        split3(pr, hh, mm, ll);
        const int cc = c16 + 16 * c;
        P0[row * 520 + cc] = hh;
        P1[row * 520 + cc] = mm;
        P2[row * 520 + cc] = ll;
    }
    __syncthreads();

    // ---- phase 3: O = P V ----
    const int nnt = hd >> 4;
    const int pbase = l15 * 520 + quad * 8;
    if (nnt == 48) {
        // hd=768: wave w owns nt = w+4u (u=0..11); process 4 nt per group ->
        // 4 independent MFMA chains sharing each P fragment.
#pragma unroll 1
        for (int g = 0; g < 3; ++g) {
            const int nt0  = w + g * 16;
            const int colg = h * hd + nt0 * 16 + l15;
            const size_t vb = (size_t)colg * Mc + b * SS + quad * 8;
            const size_t vs = (size_t)64 * Mc;      // 4*16 cols apart
            floatx4 o0 = zero, o1 = zero, o2 = zero, o3 = zero;
#pragma unroll 2
            for (int ks = 0; ks < 16; ++ks) {
                const int po = pbase + ks * 32;
                const short8 ph = *(const short8*)&P0[po];
                const short8 pm = *(const short8*)&P1[po];
                const short8 pl = *(const short8*)&P2[po];
                const size_t vo = vb + ks * 32;
                const short8 vh0 = *(const short8*)&VH[vo];
                const short8 vm0 = *(const short8*)&VM[vo];
                const short8 vl0 = *(const short8*)&VL[vo];
                const short8 vh1 = *(const short8*)&VH[vo + vs];
                const short8 vm1 = *(const short8*)&VM[vo + vs];
                const short8 vl1 = *(const short8*)&VL[vo + vs];
                const short8 vh2 = *(const short8*)&VH[vo + 2 * vs];
                const short8 vm2 = *(const short8*)&VM[vo + 2 * vs];
                const short8 vl2 = *(const short8*)&VL[vo + 2 * vs];
                const short8 vh3 = *(const short8*)&VH[vo + 3 * vs];
                const short8 vm3 = *(const short8*)&VM[vo + 3 * vs];
                const short8 vl3 = *(const short8*)&VL[vo + 3 * vs];
                o0 = MFMA16(ph, vh0, o0);
                o1 = MFMA16(ph, vh1, o1);
                o2 = MFMA16(ph, vh2, o2);
                o3 = MFMA16(ph, vh3, o3);
                o0 = MFMA16(ph, vm0, o0);
                o1 = MFMA16(ph, vm1, o1);
                o2 = MFMA16(ph, vm2, o2);
                o3 = MFMA16(ph, vm3, o3);
                o0 = MFMA16(pm, vh0, o0);
                o1 = MFMA16(pm, vh1, o1);
                o2 = MFMA16(pm, vh2, o2);
                o3 = MFMA16(pm, vh3, o3);
                o0 = MFMA16(ph, vl0, o0);
                o1 = MFMA16(ph, vl1, o1);
                o2 = MFMA16(ph, vl2, o2);
                o3 = MFMA16(ph, vl3, o3);
                o0 = MFMA16(pl, vh0, o0);
                o1 = MFMA16(pl, vh1, o1);
                o2 = MFMA16(pl, vh2, o2);
                o3 = MFMA16(pl, vh3, o3);
                o0 = MFMA16(pm, vm0, o0);
                o1 = MFMA16(pm, vm1, o1);
                o2 = MFMA16(pm, vm2, o2);
                o3 = MFMA16(pm, vm3, o3);
            }
#pragma unroll
            for (int r = 0; r < 4; ++r) {
                const int orow = b * SS + q0 + quad * 4 + r;
                float* const op = O + (size_t)orow * 768 + colg;
                op[0]   = o0[r];
                op[64]  = o1[r];
                op[128] = o2[r];
                op[192] = o3[r];
            }
        }
    } else {
        // hd=96 (H=8): small nnt — original loop.
        for (int nt = w; nt < nnt; nt += 4) {
            floatx4 o = zero;
            const int colg = h * hd + nt * 16 + l15;
            const size_t vb = (size_t)colg * Mc + b * SS;
#pragma unroll 2
            for (int ks = 0; ks < 16; ++ks) {
                const int ko = ks * 32 + quad * 8;
                const short8 ph = *(const short8*)&P0[l15 * 520 + ko];
                const short8 pm = *(const short8*)&P1[l15 * 520 + ko];
                const short8 pl = *(const short8*)&P2[l15 * 520 + ko];
                const short8 vh = *(const short8*)&VH[vb + ko];
                const short8 vm = *(const short8*)&VM[vb + ko];
                const short8 vl = *(const short8*)&VL[vb + ko];
                o = MFMA16(ph, vh, o);
                o = MFMA16(ph, vm, o);
                o = MFMA16(pm, vh, o);
                o = MFMA16(ph, vl, o);
                o = MFMA16(pl, vh, o);
                o = MFMA16(pm, vm, o);
            }
#pragma unroll
            for (int r = 0; r < 4; ++r) {
                const int orow = b * SS + q0 + quad * 4 + r;
                O[(size_t)orow * 768 + colg] = o[r];
            }
        }
    }
}

// ---------------------------------------------------------------------------
// SLOW (R0) fused attention: Q,K f32 row-major; V f32 transposed [768][Mc].
// ---------------------------------------------------------------------------
__global__ __launch_bounds__(256) void attn_k(
    const float* __restrict__ Q, const float* __restrict__ Kp,
    const float* __restrict__ Vt, float* __restrict__ O,
    int H, int hd, int Mc)
{
    __shared__ __align__(16) float S[16][520];
    __shared__ __align__(16) USH P2buf[16 * 520];
    __shared__ float red[16][16];
    __shared__ float stat[16];

    const int tid  = threadIdx.x;
    const int lane = tid & 63;
    const int w    = tid >> 6;
    const int quad = lane >> 4, l15 = lane & 15;
    const int b = blockIdx.y / H;
    const int h = blockIdx.y - b * H;
    const int q0 = blockIdx.x * 16;

    const floatx4 zero = {0.f, 0.f, 0.f, 0.f};

    floatx4 acc[8];
#pragma unroll
    for (int t = 0; t < 8; ++t) acc[t] = zero;

    const size_t qbase = ((size_t)(b * SS + q0 + l15)) * DD + h * hd;
    const int nks = hd >> 5;
    for (int ks = 0; ks < nks; ++ks) {
        const int co = ks * 32 + quad * 8;
        float qv[8];
        *(float4*)&qv[0] = *(const float4*)(Q + qbase + co);
        *(float4*)&qv[4] = *(const float4*)(Q + qbase + co + 4);
        short8 qh, qm, ql;
        split3x8(qv, qh, qm, ql);
#pragma unroll
        for (int t = 0; t < 8; ++t) {
            const size_t kb = ((size_t)(b * SS + w * 128 + t * 16 + l15)) * DD + h * hd + co;
            float kv[8];
            *(float4*)&kv[0] = *(const float4*)(Kp + kb);
            *(float4*)&kv[4] = *(const float4*)(Kp + kb + 4);
            short8 kh, km, kl;
            split3x8(kv, kh, km, kl);
            acc[t] = MFMA16(qh, kh, acc[t]);
            acc[t] = MFMA16(qh, km, acc[t]);
            acc[t] = MFMA16(qm, kh, acc[t]);
            acc[t] = MFMA16(qh, kl, acc[t]);
            acc[t] = MFMA16(ql, kh, acc[t]);
            acc[t] = MFMA16(qm, km, acc[t]);
        }
    }
#pragma unroll
    for (int t = 0; t < 8; ++t)
#pragma unroll
        for (int r = 0; r < 4; ++r)
            S[quad * 4 + r][w * 128 + t * 16 + l15] = acc[t][r] * 8.0f;
    __syncthreads();

    const int row = tid >> 4, c16 = tid & 15;
    const int cb = c16 * 32;
    float mx = -3.4e38f;
#pragma unroll 8
    for (int c = 0; c < 32; ++c) mx = fmaxf(mx, S[row][cb + c]);
    red[row][c16] = mx;
    __syncthreads();
    if (c16 == 0) {
        float m2 = red[row][0];
#pragma unroll
        for (int j = 1; j < 16; ++j) m2 = fmaxf(m2, red[row][j]);
        stat[row] = m2;
    }
    __syncthreads();
    mx = stat[row];
    float ev[32];
    float sum = 0.f;
#pragma unroll 8
    for (int c = 0; c < 32; ++c) {
        ev[c] = expf(S[row][cb + c] - mx);
        sum += ev[c];
    }
    red[row][c16] = sum;
    __syncthreads();
    if (c16 == 0) {
        float s2 = 0.f;
#pragma unroll
        for (int j = 0; j < 16; ++j) s2 += red[row][j];
        stat[row] = s2;
    }
    __syncthreads();
    const float den = stat[row];
    USH* const P0 = (USH*)&S[0][0];
    USH* const P1 = P0 + 16 * 520;
    USH* const P2 = P2buf;
#pragma unroll 8
    for (int c = 0; c < 32; ++c) {
        const float pr = ev[c] / den;
        USH hh, mm, ll;
        split3(pr, hh, mm, ll);
        P0[row * 520 + cb + c] = hh;
        P1[row * 520 + cb + c] = mm;
        P2[row * 520 + cb + c] = ll;
    }
    __syncthreads();

    const int nnt = hd >> 4;
    for (int nt = w; nt < nnt; nt += 4) {
        floatx4 o = zero;
        const int colg = h * hd + nt * 16 + l15;
        const size_t vb = (size_t)colg * Mc + b * SS;
        for (int ks = 0; ks < 16; ++ks) {
            const int ko = ks * 32 + quad * 8;
            const short8 ph = *(const short8*)&P0[l15 * 520 + ko];
            const short8 pm = *(const short8*)&P1[l15 * 520 + ko];
            const short8 pl = *(const short8*)&P2[l15 * 520 + ko];
            float vv[8];
            *(float4*)&vv[0] = *(const float4*)(Vt + vb + ko);
            *(float4*)&vv[4] = *(const float4*)(Vt + vb + ko + 4);
            short8 vh, vm, vl;
            split3x8(vv, vh, vm, vl);
            o = MFMA16(ph, vh, o);
            o = MFMA16(ph, vm, o);
            o = MFMA16(pm, vh, o);
            o = MFMA16(ph, vl, o);
            o = MFMA16(pl, vh, o);
            o = MFMA16(pm, vm, o);
        }
#pragma unroll
        for (int r = 0; r < 4; ++r) {
            const int orow = b * SS + q0 + quad * 4 + r;
            O[(size_t)orow * 768 + colg] = o[r];
        }
    }
}

// ---------------------------------------------------------------------------
// Gate: x = x * softmax(x, row) + x, in-place f32. 1 block / row.
// ---------------------------------------------------------------------------
__global__ __launch_bounds__(256) void gate_k(float* __restrict__ X) {
    __shared__ float red[256];
    const int r = blockIdx.x, tid = threadIdx.x;
    const size_t base = (size_t)r * DD;
    float x[3];
#pragma unroll
    for (int j = 0; j < 3; ++j) x[j] = X[base + tid + j * 256];
    float mx = fmaxf(x[0], fmaxf(x[1], x[2]));
    red[tid] = mx;
    __syncthreads();
    for (int s = 128; s > 0; s >>= 1) {
        if (tid < s) red[tid] = fmaxf(red[tid], red[tid + s]);
        __syncthreads();
    }
    mx = red[0];
    __syncthreads();
    float e[3];
    float sum = 0.f;
#pragma unroll
    for (int j = 0; j < 3; ++j) { e[j] = expf(x[j] - mx); sum += e[j]; }
    red[tid] = sum;
    __syncthreads();
    for (int s = 128; s > 0; s >>= 1) {
        if (tid < s) red[tid] += red[tid + s];
        __syncthreads();
    }
    const float den = red[0];
#pragma unroll
    for (int j = 0; j < 3; ++j)
        X[base + tid + j * 256] = x[j] * (e[j] / den) + x[j];
}

// ---------------------------------------------------------------------------
// Final: es = text + F1 + F2 + F3 ;  out = es * softmax(es,row) + es  (f32)
// ---------------------------------------------------------------------------
__global__ __launch_bounds__(256) void final_k(
    const float* __restrict__ text,
    const float* __restrict__ F1, const float* __restrict__ F2,
    const float* __restrict__ F3, float* __restrict__ out)
{
    __shared__ float red[256];
    const int r = blockIdx.x, tid = threadIdx.x;
    const size_t base = (size_t)r * DD;
    float x[3];
#pragma unroll
    for (int j = 0; j < 3; ++j) {
        const int c = tid + j * 256;
        x[j] = ((text[base + c] + F1[base + c]) + F2[base + c]) + F3[base + c];
    }
    float mx = fmaxf(x[0], fmaxf(x[1], x[2]));
    red[tid] = mx;
    __syncthreads();
    for (int s = 128; s > 0; s >>= 1) {
        if (tid < s) red[tid] = fmaxf(red[tid], red[tid + s]);
        __syncthreads();
    }
    mx = red[0];
    __syncthreads();
    float e[3];
    float sum = 0.f;
#pragma unroll
    for (int j = 0; j < 3; ++j) { e[j] = expf(x[j] - mx); sum += e[j]; }
    red[tid] = sum;
    __syncthreads();
    for (int s = 128; s > 0; s >>= 1) {
        if (tid < s) red[tid] += red[tid + s];
        __syncthreads();
    }
    const float den = red[0];
#pragma unroll
    for (int j = 0; j < 3; ++j) {
        const int c = tid + j * 256;
        out[base + c] = x[j] * (e[j] / den) + x[j];
    }
}

// ===========================================================================
// Host orchestration — dual path.
// ===========================================================================
extern "C" void kernel_launch(void* const* d_in, const int* in_sizes, int n_in,
                              void* d_out, int out_size, void* d_ws, size_t ws_size,
                              hipStream_t stream)
{
    (void)in_sizes; (void)n_in; (void)out_size;

    const float* text    = (const float*)d_in[0];
    const int*   vis_ids = (const int*)d_in[1];
    const int*   ac_ids  = (const int*)d_in[2];
    const float* vis_tab = (const float*)d_in[3];
    const float* ac_tab  = (const float*)d_in[4];
    const float* hv_wq = (const float*)d_in[5],  *hv_bq = (const float*)d_in[6];
    const float* hv_wk = (const float*)d_in[7],  *hv_bk = (const float*)d_in[8];
    const float* hv_wv = (const float*)d_in[9],  *hv_bv = (const float*)d_in[10];
    const float* ha_wq = (const float*)d_in[11], *ha_bq = (const float*)d_in[12];
    const float* ha_wk = (const float*)d_in[13], *ha_bk = (const float*)d_in[14];
    const float* ha_wv = (const float*)d_in[15], *ha_bv = (const float*)d_in[16];
    const float* ht_wq = (const float*)d_in[17], *ht_bq = (const float*)d_in[18];
    const float* ht_wk = (const float*)d_in[19], *ht_bk = (const float*)d_in[20];
    const float* ht_wv = (const float*)d_in[21], *ht_bv = (const float*)d_in[22];
    const float* ht_fcw = (const float*)d_in[23], *ht_fcb = (const float*)d_in[24];
    const float* ffn_w1 = (const float*)d_in[25], *ffn_b1 = (const float*)d_in[26];
    const float* ffn_w2 = (const float*)d_in[27], *ffn_b2 = (const float*)d_in[28];
    const float* cat_w  = (const float*)d_in[29], *cat_b  = (const float*)d_in[30];

    // ---------------- workspace sizing ----------------
    // ws in [227.3MB (R2 fast fit proven), 276MB).  fast@8192 = 227.3MB.
    const size_t SQ   = (size_t)768 * 768;                     // USH per plane
    const size_t WUSH = 3 * (12 * SQ + (size_t)768 * 1536);    // 24,772,608 USH
    const size_t TABF = (size_t)512 * 384 * 2;                 // floats
    int Mc = 0, fast = 0;
    for (int cand = MM; cand >= 512; cand >>= 1) {
        const size_t nf = WUSH * sizeof(USH) + TABF * 4 + (size_t)cand * 768 * 28;
        const size_t ns = WUSH * sizeof(USH) + (size_t)cand * 768 * 24;
        if (nf <= ws_size) { Mc = cand; fast = 1; break; }
        if (ns <= ws_size) { Mc = cand; fast = 0; break; }
    }
    if (Mc == 0) return;    // diagnostic: wrong output, not a fault
    const int nchunk = MM / Mc;
    const int chB    = Mc / SS;

    USH* p = (USH*)d_ws;
    USH *wt0[13], *wt1[13], *wt2[13];
    for (int i = 0; i < 13; ++i) {
        const size_t sz = (i == 12) ? (size_t)768 * 1536 : SQ;
        wt0[i] = p; p += sz;
        wt1[i] = p; p += sz;
        wt2[i] = p; p += sz;
    }

    // weight indices: 0 hv_wq 1 hv_wk 2 hv_wv 3 ha_wq 4 ha_wk 5 ha_wv
    //                 6 ht_wq 7 ht_wk 8 ht_wv 9 ht_fcw 10 ffn_w1 11 ffn_w2 12 cat_w
    TransArgs ta;
    const float* tin[13] = {hv_wq, hv_wk, hv_wv, ha_wq, ha_wk, ha_wv,
                            ht_wq, ht_wk, ht_wv, ht_fcw, ffn_w1, ffn_w2, cat_w};
    for (int i = 0; i < 13; ++i) {
        ta.in[i] = tin[i]; ta.o0[i] = wt0[i]; ta.o1[i] = wt1[i]; ta.o2[i] = wt2[i];
        ta.R[i] = (i == 12) ? 1536 : 768;
    }
    trans_k<<<dim3(48, 24, 13), 256, 0, stream>>>(ta);

    const size_t PSZ = (size_t)Mc * 768;       // elements per plane
    const dim3 gg(Mc / 128, DD / 128), gb(256);
    const int ropeg = Mc * 384 / 256;
    const float* NULF = nullptr;
    USH* const NUSH = nullptr;

    if (fast) {
        // layout: weights | tab | A,B,C,F f32 | KH KM KL VH VM VL bf16
        float* tab = (float*)p;
        float* fp  = tab + TABF;
        float *A_ = fp + 0 * PSZ, *B_ = fp + 1 * PSZ;
        float *C_ = fp + 2 * PSZ, *F_ = fp + 3 * PSZ;
        USH* KH = (USH*)(fp + 4 * PSZ);
        USH* KM = KH + PSZ;  USH* KL = KM + PSZ;
        USH* VH = KL + PSZ;  USH* VM = VH + PSZ;  USH* VL = VM + PSZ;

        tab_k<<<(512 * 384) / 256, 256, 0, stream>>>(tab);

// plain GEMM (f32 out)
#define GE(A0P, A1P, WI, LDB, BIAS, CP, KK, ACT) \
    gemm_k<<<gg, gb, 0, stream>>>(A0P, A1P, wt0[WI], wt1[WI], wt2[WI], LDB, BIAS, \
                                  CP, NUSH, NUSH, NUSH, tab, KK, ACT, 0, 0, Mc)
// Q GEMM: rope fused, f32 out
#define GQ(A0P, WI, BIAS, CP) \
    gemm_k<<<gg, gb, 0, stream>>>(A0P, NULF, wt0[WI], wt1[WI], wt2[WI], 768, BIAS, \
                                  CP, NUSH, NUSH, NUSH, tab, 768, 0, 0, 1, Mc)
// K GEMM: rope fused, row-major 3-plane bf16 out
#define GK(A0P, WI, BIAS) \
    gemm_k<<<gg, gb, 0, stream>>>(A0P, NULF, wt0[WI], wt1[WI], wt2[WI], 768, BIAS, \
                                  (float*)nullptr, KH, KM, KL, tab, 768, 0, 3, 1, Mc)
// V GEMM: transposed 3-plane bf16 out (LDS-coalesced epilogue)
#define GV(A0P, WI, BIAS) \
    gemm_k<<<gg, gb, 0, stream>>>(A0P, NULF, wt0[WI], wt1[WI], wt2[WI], 768, BIAS, \
                                  (float*)nullptr, VH, VM, VL, tab, 768, 0, 1, 0, Mc)
#define ATTNF(QP, OP, HH, HD) \
    attn_fast_k<<<dim3(SS / 16, chB * (HH)), 256, 0, stream>>>(QP, KH, KM, KL, \
                                                  VH, VM, VL, OP, HH, HD, Mc)
#define GATE(XP) gate_k<<<Mc, 256, 0, stream>>>(XP)

        for (int c = 0; c < nchunk; ++c) {
            const float* tx = text + (size_t)c * PSZ;
            const int* vi = vis_ids + (size_t)c * Mc;
            const int* ai = ac_ids  + (size_t)c * Mc;
            float* outc = (float*)d_out + (size_t)c * PSZ;   // scratch till final

            gather_k<<<Mc * 192 / 256, 256, 0, stream>>>(vi, vis_tab, A_);  // Ev
            gather_k<<<Mc * 192 / 256, 256, 0, stream>>>(ai, ac_tab, B_);   // Ea

            // ---- v1 = hv(text, Ev) -> F_ ----
            GQ(tx, 0, hv_bq, C_);
            GK(A_, 1, hv_bk);  GV(A_, 2, hv_bv);
            ATTNF(C_, F_, 1, 768);                           // (Ev dead)

            // ---- a1 = ha(text, Ea) -> A_ ----
            GQ(tx, 3, ha_bq, C_);
            GK(B_, 4, ha_bk);  GV(B_, 5, ha_bv);
            ATTNF(C_, A_, 1, 768);                           // (Ea dead)

            // ---- v2 = hv(v1, a1) -> C_ (aliases its Q) ----
            GQ(F_, 0, hv_bq, C_);
            GK(A_, 1, hv_bk);  GV(A_, 2, hv_bv);
            ATTNF(C_, C_, 1, 768);

            // ---- a2 = ha(a1, v1) -> B_ (aliases its Q) ----
            GQ(A_, 3, ha_bq, B_);
            GK(F_, 4, ha_bk);  GV(F_, 5, ha_bv);
            ATTNF(B_, B_, 1, 768);

            // ---- F1 = ffn(gate(cat(v1,a1) @ cat_w)) -> A_ ----
            GE(F_, A_, 12, 1536, cat_b, outc, 1536, 0);      // T1
            GATE(outc);
            GE(outc, NULF, 10, 768, ffn_b1, F_, 768, 1);     // H (v1 dead)
            GE(F_, NULF, 11, 768, ffn_b2, A_, 768, 0);       // F1 -> A_ (a1 dead)

            // ---- F2 = ffn(gate(cat(v2,a2) @ cat_w)) -> C_ ----
            GE(C_, B_, 12, 1536, cat_b, outc, 1536, 0);      // T2
            GATE(outc);
            GE(outc, NULF, 10, 768, ffn_b1, F_, 768, 1);     // H
            GE(F_, NULF, 11, 768, ffn_b2, C_, 768, 0);       // F2 -> C_ (v2 dead)

            // ---- F3 = ffn(gate(fc(ht(F1, text)))) -> F_ ----
            GQ(A_, 6, ht_bq, B_);                            // Q <- F1 (a2 dead)
            GK(tx, 7, ht_bk);  GV(tx, 8, ht_bv);
            ATTNF(B_, B_, 8, 96);                            // AO aliases Q
            GE(B_, NULF, 9, 768, ht_fcb, F_, 768, 0);        // fc
            GATE(F_);
            GE(F_, NULF, 10, 768, ffn_b1, B_, 768, 1);       // H
            GE(B_, NULF, 11, 768, ffn_b2, F_, 768, 0);       // F3

            final_k<<<Mc, 256, 0, stream>>>(tx, A_, C_, F_, outc);
        }
#undef GE
#undef GQ
#undef GK
#undef GV
#undef ATTNF
#undef GATE
    } else {
        // -------- SLOW path: exact R0 (6 f32 planes, on-the-fly splits) ------
        float* fp = (float*)p;
        float *A_ = fp + 0 * PSZ, *B_ = fp + 1 * PSZ, *C_ = fp + 2 * PSZ;
        float *D_ = fp + 3 * PSZ, *E_ = fp + 4 * PSZ, *F_ = fp + 5 * PSZ;

#define GEMM(A0P, A1P, WI, LDB, BIAS, CP, KK, ACT, TOUT) \
    gemm_k<<<gg, gb, 0, stream>>>(A0P, A1P, wt0[WI], wt1[WI], wt2[WI], LDB, BIAS, \
                                  CP, NUSH, NUSH, NUSH, NULF, KK, ACT, TOUT, 0, Mc)
#define ROPE(XP) rope_k<<<ropeg, 256, 0, stream>>>(XP)
#define ATTN(QP, KP, VP, OP, HH, HD) \
    attn_k<<<dim3(SS / 16, chB * (HH)), 256, 0, stream>>>(QP, KP, VP, OP, HH, HD, Mc)
#define GATE(XP) gate_k<<<Mc, 256, 0, stream>>>(XP)

        for (int c = 0; c < nchunk; ++c) {
            const float* tx = text + (size_t)c * PSZ;
            const int* vi = vis_ids + (size_t)c * Mc;
            const int* ai = ac_ids  + (size_t)c * Mc;
            float* outc = (float*)d_out + (size_t)c * PSZ;

            gather_k<<<Mc * 192 / 256, 256, 0, stream>>>(vi, vis_tab, A_);
            gather_k<<<Mc * 192 / 256, 256, 0, stream>>>(ai, ac_tab, B_);

            GEMM(tx, NULF, 0, 768, hv_bq, C_, 768, 0, 0);
            GEMM(A_, NULF, 1, 768, hv_bk, D_, 768, 0, 0);
            GEMM(A_, NULF, 2, 768, hv_bv, E_, 768, 0, 2);
            ROPE(C_); ROPE(D_);
            ATTN(C_, D_, E_, F_, 1, 768);

            GEMM(tx, NULF, 3, 768, ha_bq, C_, 768, 0, 0);
            GEMM(B_, NULF, 4, 768, ha_bk, D_, 768, 0, 0);
            GEMM(B_, NULF, 5, 768, ha_bv, E_, 768, 0, 2);
            ROPE(C_); ROPE(D_);
            ATTN(C_, D_, E_, A_, 1, 768);

            GEMM(F_, NULF, 0, 768, hv_bq, C_, 768, 0, 0);
            GEMM(A_, NULF, 1, 768, hv_bk, D_, 768, 0, 0);
            GEMM(A_, NULF, 2, 768, hv_bv, E_, 768, 0, 2);
            ROPE(C_); ROPE(D_);
            ATTN(C_, D_, E_, C_, 1, 768);

            GEMM(A_, NULF, 3, 768, ha_bq, B_, 768, 0, 0);
            GEMM(F_, NULF, 4, 768, ha_bk, D_, 768, 0, 0);
            GEMM(F_, NULF, 5, 768, ha_bv, E_, 768, 0, 2);
            ROPE(B_); ROPE(D_);
            ATTN(B_, D_, E_, B_, 1, 768);

            GEMM(F_, A_, 12, 1536, cat_b, D_, 1536, 0, 0);
            GATE(D_);
            GEMM(D_, NULF, 10, 768, ffn_b1, E_, 768, 1, 0);
            GEMM(E_, NULF, 11, 768, ffn_b2, F_, 768, 0, 0);

            GEMM(C_, B_, 12, 1536, cat_b, A_, 1536, 0, 0);
            GATE(A_);
            GEMM(A_, NULF, 10, 768, ffn_b1, C_, 768, 1, 0);
            GEMM(C_, NULF, 11, 768, ffn_b2, B_, 768, 0, 0);

            GEMM(F_, NULF, 6, 768, ht_bq, C_, 768, 0, 0);
            GEMM(tx, NULF, 7, 768, ht_bk, D_, 768, 0, 0);
            GEMM(tx, NULF, 8, 768, ht_bv, E_, 768, 0, 2);
            ROPE(C_); ROPE(D_);
            ATTN(C_, D_, E_, C_, 8, 96);
            GEMM(C_, NULF, 9, 768, ht_fcb, A_, 768, 0, 0);
            GATE(A_);
            GEMM(A_, NULF, 10, 768, ffn_b1, C_, 768, 1, 0);
            GEMM(C_, NULF, 11, 768, ffn_b2, D_, 768, 0, 0);

            final_k<<<Mc, 256, 0, stream>>>(tx, F_, B_, D_, outc);
        }
#undef GEMM
#undef ROPE
#undef ATTN
#undef GATE
    }
}

// Round 6
// 6466.927 us; speedup vs baseline: 1.1539x; 1.1539x over previous
//
#include <hip/hip_runtime.h>
#include <stdint.h>
#include <math.h>

// ============================================================================
// MCFNet on MI355X (gfx950).  INPUTS FLOAT32; OUTPUT FLOAT32.
// Numerics: all tensors stored f32.  Every matmul runs on MFMA bf16 with
// 3-plane splits (x = h + m + l, rep error ~2^-27) and 6 passes
// (hh, hm, mh, hl, lh, mm).  Weights pre-split into 3 transposed bf16 planes.
//
// R6: hd=768 attention re-expressed on the proven gemm_k engine (the fused
// attn block was grid-starved at 2 blocks/CU and ~30x stall-dominated):
//   1) score GEMM  S = (Q @ K^T)*8  (batched per-b B offset, ldc=512) -> outc
//   2) smax_k      row softmax + split3 -> P planes (overwrite dead K planes)
//   3) PV GEMM     O = P @ V  (pre-split-A staging, B = V^T planes, K=512)
// Accumulation orders identical to the fused kernel (bit-identical scores/O;
// softmax denominator tree-sum differs ~1ulp — evidenced safe in R5).
// H=8 attention keeps R4's attn_fast_k (grid 4096, occupancy fine).
// gemm_k main loop untouched; epilogue gains scale/ldc/batched-B/pre-split-A.
// ============================================================================

typedef unsigned short USH;
typedef __attribute__((ext_vector_type(8))) short short8;
typedef __attribute__((ext_vector_type(4))) float floatx4;

#define MFMA16(a, b, c) __builtin_amdgcn_mfma_f32_16x16x32_bf16((a), (b), (c), 0, 0, 0)

static constexpr int NB = 32;          // batch
static constexpr int SS = 512;         // seq len
static constexpr int DD = 768;         // model dim
static constexpr int MM = NB * SS;     // 16384 rows

__device__ __forceinline__ float bf2f(USH h) {
    return __uint_as_float(((unsigned)h) << 16);
}
__device__ __forceinline__ USH f2bf(float x) {          // round-to-nearest-even
    unsigned u = __float_as_uint(x);
    return (USH)((u + 0x7fffu + ((u >> 16) & 1u)) >> 16);
}
// 3-plane split: x = h + m + l + err, |err| <= 2^-27 |x| (residuals exact).
__device__ __forceinline__ void split3(float x, USH &h, USH &m, USH &l) {
    h = f2bf(x);
    const float r1 = x - bf2f(h);
    m = f2bf(r1);
    const float r2 = r1 - bf2f(m);
    l = f2bf(r2);
}
__device__ __forceinline__ void split3x8(const float* v, short8 &H, short8 &M, short8 &L) {
#pragma unroll
    for (int j = 0; j < 8; ++j) {
        USH h, m, l;
        split3(v[j], h, m, l);
        H[j] = (short)h; M[j] = (short)m; L[j] = (short)l;
    }
}
__device__ __forceinline__ uint2 pk4(USH a, USH b, USH c, USH d) {
    uint2 r;
    r.x = (unsigned)a | ((unsigned)b << 16);
    r.y = (unsigned)c | ((unsigned)d << 16);
    return r;
}

// ---------------------------------------------------------------------------
// Weight transpose+split: f32 [R][768] -> 3 bf16 planes [768][R].
// ---------------------------------------------------------------------------
struct TransArgs {
    const float* in[13];
    USH* o0[13]; USH* o1[13]; USH* o2[13];
    int R[13];
};

__global__ __launch_bounds__(256) void trans_k(TransArgs a) {
    const int mi = blockIdx.z;
    const float* __restrict__ in = a.in[mi];
    USH* __restrict__ o0 = a.o0[mi];
    USH* __restrict__ o1 = a.o1[mi];
    USH* __restrict__ o2 = a.o2[mi];
    const int R = a.R[mi];
    const int bx = blockIdx.x, by = blockIdx.y;
    if (bx * 32 >= R) return;
    __shared__ float t[32][33];
    const int tx = threadIdx.x & 31, ty = threadIdx.x >> 5;   // 32 x 8
#pragma unroll
    for (int i = 0; i < 4; ++i)
        t[ty + i * 8][tx] = in[(size_t)(bx * 32 + ty + i * 8) * 768 + by * 32 + tx];
    __syncthreads();
#pragma unroll
    for (int i = 0; i < 4; ++i) {
        USH h, m, l;
        split3(t[tx][ty + i * 8], h, m, l);
        const size_t o = (size_t)(by * 32 + ty + i * 8) * R + bx * 32 + tx;
        o0[o] = h; o1[o] = m; o2[o] = l;
    }
}

// ---------------------------------------------------------------------------
// Embedding gather: dst[m,:] = table[ids[m],:]  (f32 copy)
// ---------------------------------------------------------------------------
__global__ __launch_bounds__(256) void gather_k(const int* __restrict__ ids,
                                                const float* __restrict__ table,
                                                float* __restrict__ dst) {
    const int g  = blockIdx.x * 256 + threadIdx.x;
    const int m  = g / 192;
    const int c4 = (g - m * 192) * 4;
    const int id = ids[m];
    *(float4*)(dst + (size_t)m * DD + c4) =
        *(const float4*)(table + (size_t)id * DD + c4);
}

// ---------------------------------------------------------------------------
// RoPE cos/sin table: tab[s][i] = {cos,sin}(s * theta_i), 512 x 384.
// ---------------------------------------------------------------------------
__global__ __launch_bounds__(256) void tab_k(float* __restrict__ tab) {
    const int p = blockIdx.x * 256 + threadIdx.x;
    const int s = p / 384;
    const int i = p - s * 384;
    const float ef = (-2.0f * (float)i) / 768.0f;
    const float th = (float)pow(10000.0, (double)ef);
    const float ang = (float)s * th;
    float sn, cs;
    sincosf(ang, &sn, &cs);
    tab[2 * p]     = cs;
    tab[2 * p + 1] = sn;
}

// Slow-path RoPE (R0, pow per thread), in-place f32.
__global__ __launch_bounds__(256) void rope_k(float* __restrict__ X) {
    const int p = blockIdx.x * 256 + threadIdx.x;
    const int m = p / 384;
    const int i = p - m * 384;
    const int s = m & (SS - 1);
    const float ef = (-2.0f * (float)i) / 768.0f;
    const float th = (float)pow(10000.0, (double)ef);
    const float ang = (float)s * th;
    float sn, cs;
    sincosf(ang, &sn, &cs);
    float2 x = *(float2*)(X + (size_t)m * DD + 2 * i);
    float2 y;
    y.x = x.x * cs - x.y * sn;
    y.y = x.y * cs + x.x * sn;
    *(float2*)(X + (size_t)m * DD + 2 * i) = y;
}

// ---------------------------------------------------------------------------
// GEMM: C[Mc,N] = A[Mc,K] @ W[K,N] + bias.
// A: f32 (A0/A1 concat halves, stride 768, split3 in-kernel) OR pre-split
//    3 bf16 planes AP0/1/2 with row stride lda (PV path — plane copy staging).
// B: 3 bf16 planes [N][K] stride ldb; bofs != 0 adds (gm0/512)*bofs to the
//    plane base (batched per-b operand for attention score / PV GEMMs).
// Epilogue: x = acc*scale + bias; act 1 = SiLU; rope 1 = fused RoPE (tab).
// tout: 0 f32 C[row*ldc+col]; 1 transposed 3-plane bf16 via LDS (V^T);
//       2 transposed f32 (slow path V^T); 3 row-major 3-plane bf16 (K planes).
// XCD-chunked bijective block swizzle (grid %8 == 0).
// ---------------------------------------------------------------------------
__global__ __launch_bounds__(256) void gemm_k(
    const float* __restrict__ A0, const float* __restrict__ A1,
    const USH* __restrict__ AP0, const USH* __restrict__ AP1,
    const USH* __restrict__ AP2, int lda,
    const USH* __restrict__ B0, const USH* __restrict__ B1, const USH* __restrict__ B2,
    int ldb, size_t bofs,
    const float* __restrict__ bias, float scale,
    float* __restrict__ C, int ldc,
    USH* __restrict__ S0p, USH* __restrict__ S1p, USH* __restrict__ S2p,
    const float* __restrict__ tab,
    int K, int act, int tout, int rope, int Mc)
{
    __shared__ __align__(16) USH smem[24576];
    USH* const sA0 = smem;
    USH* const sA1 = smem + 4096;
    USH* const sA2 = smem + 8192;
    USH* const sB0 = smem + 12288;
    USH* const sB1 = smem + 16384;
    USH* const sB2 = smem + 20480;

    const int tid  = threadIdx.x;
    const int lane = tid & 63;
    const int w    = tid >> 6;
    const int quad = lane >> 4, l15 = lane & 15;
    const int wm = (w >> 1) * 64, wn = (w & 1) * 64;

    // XCD-chunked bijective swizzle: consecutive work-ids share an XCD's L2.
    const int nbx = gridDim.x;
    const int tot = nbx * (int)gridDim.y;
    int bid = blockIdx.y * nbx + blockIdx.x;
    if ((tot & 7) == 0) bid = (bid & 7) * (tot >> 3) + (bid >> 3);
    const int byy = bid / nbx;
    const int gm0 = (bid - byy * nbx) * 128, gn0 = byy * 128;

    // batched per-b B operand (attention score / PV GEMMs)
    const USH* __restrict__ Bp0 = B0;
    const USH* __restrict__ Bp1 = B1;
    const USH* __restrict__ Bp2 = B2;
    if (bofs) {
        const size_t ad = (size_t)(gm0 >> 9) * bofs;
        Bp0 += ad; Bp1 += ad; Bp2 += ad;
    }

    const int i0 = tid * 2, i1 = tid * 2 + 1;
    const int r0 = i0 >> 2, c0 = (i0 & 3) << 3;
    const int r1 = i1 >> 2, c1 = (i1 & 3) << 3;

    const floatx4 zero = {0.f, 0.f, 0.f, 0.f};
    floatx4 acc[4][4];
#pragma unroll
    for (int i = 0; i < 4; ++i)
#pragma unroll
        for (int j = 0; j < 4; ++j) acc[i][j] = zero;

    for (int k0 = 0; k0 < K; k0 += 32) {
        // ---- B staging: 3 pre-split planes, 2 uint4 per plane per thread ----
        *(uint4*)&sB0[r0 * 32 + c0] = *(const uint4*)(Bp0 + (size_t)(gn0 + r0) * ldb + k0 + c0);
        *(uint4*)&sB0[r1 * 32 + c1] = *(const uint4*)(Bp0 + (size_t)(gn0 + r1) * ldb + k0 + c1);
        *(uint4*)&sB1[r0 * 32 + c0] = *(const uint4*)(Bp1 + (size_t)(gn0 + r0) * ldb + k0 + c0);
        *(uint4*)&sB1[r1 * 32 + c1] = *(const uint4*)(Bp1 + (size_t)(gn0 + r1) * ldb + k0 + c1);
        *(uint4*)&sB2[r0 * 32 + c0] = *(const uint4*)(Bp2 + (size_t)(gn0 + r0) * ldb + k0 + c0);
        *(uint4*)&sB2[r1 * 32 + c1] = *(const uint4*)(Bp2 + (size_t)(gn0 + r1) * ldb + k0 + c1);

        if (AP0) {
            // ---- A staging: pre-split planes, plane copy (PV path) ----
            *(uint4*)&sA0[r0 * 32 + c0] = *(const uint4*)(AP0 + (size_t)(gm0 + r0) * lda + k0 + c0);
            *(uint4*)&sA0[r1 * 32 + c1] = *(const uint4*)(AP0 + (size_t)(gm0 + r1) * lda + k0 + c1);
            *(uint4*)&sA1[r0 * 32 + c0] = *(const uint4*)(AP1 + (size_t)(gm0 + r0) * lda + k0 + c0);
            *(uint4*)&sA1[r1 * 32 + c1] = *(const uint4*)(AP1 + (size_t)(gm0 + r1) * lda + k0 + c1);
            *(uint4*)&sA2[r0 * 32 + c0] = *(const uint4*)(AP2 + (size_t)(gm0 + r0) * lda + k0 + c0);
            *(uint4*)&sA2[r1 * 32 + c1] = *(const uint4*)(AP2 + (size_t)(gm0 + r1) * lda + k0 + c1);
        } else {
            // ---- A staging: f32 -> split3 -> 3 planes; 4 float4/thread ----
            const float* __restrict__ A = (k0 < 768) ? A0 : A1;
            const int kof = (k0 < 768) ? k0 : (k0 - 768);
#pragma unroll
            for (int u = 0; u < 4; ++u) {
                const int idx = tid + u * 256;           // [0,1024)
                const int r = idx >> 3, c = (idx & 7) * 4;
                const float4 v = *(const float4*)(A + (size_t)(gm0 + r) * 768 + kof + c);
                USH h[4], m[4], l[4];
                split3(v.x, h[0], m[0], l[0]);
                split3(v.y, h[1], m[1], l[1]);
                split3(v.z, h[2], m[2], l[2]);
                split3(v.w, h[3], m[3], l[3]);
                *(uint2*)&sA0[r * 32 + c] = pk4(h[0], h[1], h[2], h[3]);
                *(uint2*)&sA1[r * 32 + c] = pk4(m[0], m[1], m[2], m[3]);
                *(uint2*)&sA2[r * 32 + c] = pk4(l[0], l[1], l[2], l[3]);
            }
        }
        __syncthreads();

        short8 a0[4], a1f[4], a2[4], b0[4], b1f[4], b2[4];
#pragma unroll
        for (int t = 0; t < 4; ++t) {
            const int ao = (wm + t * 16 + l15) * 32 + quad * 8;
            const int bo = (wn + t * 16 + l15) * 32 + quad * 8;
            a0[t]  = *(const short8*)&sA0[ao];
            a1f[t] = *(const short8*)&sA1[ao];
            a2[t]  = *(const short8*)&sA2[ao];
            b0[t]  = *(const short8*)&sB0[bo];
            b1f[t] = *(const short8*)&sB1[bo];
            b2[t]  = *(const short8*)&sB2[bo];
        }
        // 6 passes: hh, hm, mh, hl, lh, mm
#pragma unroll
        for (int i = 0; i < 4; ++i)
#pragma unroll
            for (int j = 0; j < 4; ++j) acc[i][j] = MFMA16(a0[i],  b0[j],  acc[i][j]);
#pragma unroll
        for (int i = 0; i < 4; ++i)
#pragma unroll
            for (int j = 0; j < 4; ++j) acc[i][j] = MFMA16(a0[i],  b1f[j], acc[i][j]);
#pragma unroll
        for (int i = 0; i < 4; ++i)
#pragma unroll
            for (int j = 0; j < 4; ++j) acc[i][j] = MFMA16(a1f[i], b0[j],  acc[i][j]);
#pragma unroll
        for (int i = 0; i < 4; ++i)
#pragma unroll
            for (int j = 0; j < 4; ++j) acc[i][j] = MFMA16(a0[i],  b2[j],  acc[i][j]);
#pragma unroll
        for (int i = 0; i < 4; ++i)
#pragma unroll
            for (int j = 0; j < 4; ++j) acc[i][j] = MFMA16(a2[i],  b0[j],  acc[i][j]);
#pragma unroll
        for (int i = 0; i < 4; ++i)
#pragma unroll
            for (int j = 0; j < 4; ++j) acc[i][j] = MFMA16(a1f[i], b1f[j], acc[i][j]);
        __syncthreads();
    }

    // ---- epilogue ----
    if (tout == 1) {
        // V^T planes via LDS transpose -> coalesced short8 stores.
        USH* const sT = smem;                       // 128*144 = 18432 USH
#pragma unroll
        for (int p = 0; p < 3; ++p) {
            __syncthreads();
#pragma unroll
            for (int j = 0; j < 4; ++j) {
                const int col = gn0 + wn + j * 16 + l15;
                const int cl  = wn + j * 16 + l15;
                const float bv = bias ? bias[col] : 0.0f;
#pragma unroll
                for (int i = 0; i < 4; ++i) {
#pragma unroll
                    for (int r = 0; r < 4; ++r) {
                        const int rl = wm + i * 16 + quad * 4 + r;
                        USH h, m, l;
                        split3(acc[i][j][r] * scale + bv, h, m, l);
                        sT[cl * 144 + rl] = (p == 0) ? h : ((p == 1) ? m : l);
                    }
                }
            }
            __syncthreads();
            USH* const dst = (p == 0) ? S0p : ((p == 1) ? S1p : S2p);
#pragma unroll
            for (int u = 0; u < 8; ++u) {
                const int cc = u * 256 + tid;       // [0, 2048)
                const int cl = cc >> 4, off = (cc & 15) * 8;
                *(short8*)(dst + (size_t)(gn0 + cl) * Mc + gm0 + off) =
                    *(const short8*)&sT[cl * 144 + off];
            }
        }
        return;
    }

#pragma unroll
    for (int j = 0; j < 4; ++j) {
        const int col = gn0 + wn + j * 16 + l15;
        const float bv = bias ? bias[col] : 0.0f;
#pragma unroll
        for (int i = 0; i < 4; ++i) {
#pragma unroll
            for (int r = 0; r < 4; ++r) {
                const int row = gm0 + wm + i * 16 + quad * 4 + r;
                float x = acc[i][j][r] * scale + bv;
                if (act == 1) {
                    const float s = 1.0f / (1.0f + expf(-x));   // sigmoid then mul
                    x = x * s;
                }
                if (rope) {
                    // partner lane holds col^1, same row; same math as rope_k.
                    const float px = __shfl_xor(x, 1, 64);
                    const float2 t = *(const float2*)(tab +
                        2 * ((row & (SS - 1)) * 384 + (col >> 1)));
                    x = (col & 1) ? (x * t.x + px * t.y)
                                  : (x * t.x - px * t.y);
                }
                if (tout == 3) {
                    USH h, m, l;
                    split3(x, h, m, l);
                    const size_t o = (size_t)row * 768 + col;
                    S0p[o] = h; S1p[o] = m; S2p[o] = l;
                } else if (tout == 2) {
                    C[(size_t)col * Mc + row] = x;
                } else {
                    C[(size_t)row * ldc + col] = x;
                }
            }
        }
    }
}

// ---------------------------------------------------------------------------
// Row softmax + split3: S f32 [rows][512] -> P 3 bf16 planes [rows][512].
// One block per row; max exact (fmax tree), sum tree (~1ulp vs serial).
// ---------------------------------------------------------------------------
__global__ __launch_bounds__(256) void smax_k(
    const float* __restrict__ S,
    USH* __restrict__ P0, USH* __restrict__ P1, USH* __restrict__ P2)
{
    __shared__ float red[256];
    const int row = blockIdx.x, tid = threadIdx.x;
    const size_t base = (size_t)row * 512;
    const float a = S[base + tid];
    const float b = S[base + 256 + tid];
    red[tid] = fmaxf(a, b);
    __syncthreads();
    for (int s = 128; s > 0; s >>= 1) {
        if (tid < s) red[tid] = fmaxf(red[tid], red[tid + s]);
        __syncthreads();
    }
    const float mx = red[0];
    __syncthreads();
    const float e0 = expf(a - mx);
    const float e1 = expf(b - mx);
    red[tid] = e0 + e1;
    __syncthreads();
    for (int s = 128; s > 0; s >>= 1) {
        if (tid < s) red[tid] += red[tid + s];
        __syncthreads();
    }
    const float den = red[0];
    USH h, m, l;
    split3(e0 / den, h, m, l);
    P0[base + tid] = h; P1[base + tid] = m; P2[base + tid] = l;
    split3(e1 / den, h, m, l);
    P0[base + 256 + tid] = h; P1[base + 256 + tid] = m; P2[base + 256 + tid] = l;
}

// ---------------------------------------------------------------------------
// FAST fused attention (R4 body; used for the H=8 head-split attention only).
// Q f32 (split on the fly), K planes [Mc][768], V planes transposed [768][Mc].
// 2-deep pipelined K loads.  XCD swizzle.  grid: (SS/16, chB*H), block 256.
// O may alias Q (per-block row ownership).
// ---------------------------------------------------------------------------
__global__ __launch_bounds__(256) void attn_fast_k(
    const float* __restrict__ Q,
    const USH* __restrict__ KH, const USH* __restrict__ KM, const USH* __restrict__ KL,
    const USH* __restrict__ VH, const USH* __restrict__ VM, const USH* __restrict__ VL,
    float* __restrict__ O, int H, int hd, int Mc)
{
    __shared__ __align__(16) float S[16][520];      // scores; later P0|P1 overlay
    __shared__ __align__(16) USH P2buf[16 * 520];   // P lo plane
    __shared__ float red[16][16];
    __shared__ float stat[16];

    const int tid  = threadIdx.x;
    const int lane = tid & 63;
    const int w    = tid >> 6;
    const int quad = lane >> 4, l15 = lane & 15;

    const int nbx = gridDim.x;                      // SS/16 = 32
    const int tot = nbx * (int)gridDim.y;
    int bid = blockIdx.y * nbx + blockIdx.x;
    if ((tot & 7) == 0) bid = (bid & 7) * (tot >> 3) + (bid >> 3);
    const int yy = bid / nbx;
    const int q0 = (bid - yy * nbx) * 16;
    const int b = yy / H;
    const int h = yy - b * H;

    const floatx4 zero = {0.f, 0.f, 0.f, 0.f};

    // ---- phase 1: scores.  wave w covers keys [w*128, w*128+128) ----
    floatx4 acc[8];
#pragma unroll
    for (int t = 0; t < 8; ++t) acc[t] = zero;

    const size_t qbase  = ((size_t)(b * SS + q0 + l15)) * DD + h * hd;
    const size_t kstrip = ((size_t)(b * SS + w * 128 + l15)) * DD + h * hd;
    const int nks = hd >> 5;
    for (int ks = 0; ks < nks; ++ks) {
        const int co = ks * 32 + quad * 8;
        float qv[8];
        *(float4*)&qv[0] = *(const float4*)(Q + qbase + co);
        *(float4*)&qv[4] = *(const float4*)(Q + qbase + co + 4);
        short8 qh, qm, ql;
        split3x8(qv, qh, qm, ql);

        size_t ka = kstrip + co;
        short8 khc = *(const short8*)&KH[ka];
        short8 kmc = *(const short8*)&KM[ka];
        short8 klc = *(const short8*)&KL[ka];
#pragma unroll
        for (int t = 0; t < 8; ++t) {
            short8 khn = khc, kmn = kmc, kln = klc;
            if (t < 7) {
                const size_t kb = ka + (size_t)(t + 1) * 16 * DD;
                khn = *(const short8*)&KH[kb];
                kmn = *(const short8*)&KM[kb];
                kln = *(const short8*)&KL[kb];
            }
            acc[t] = MFMA16(qh, khc, acc[t]);
            acc[t] = MFMA16(qh, kmc, acc[t]);
            acc[t] = MFMA16(qm, khc, acc[t]);
            acc[t] = MFMA16(qh, klc, acc[t]);
            acc[t] = MFMA16(ql, khc, acc[t]);
            acc[t] = MFMA16(qm, kmc, acc[t]);
            __builtin_amdgcn_sched_barrier(0);   // keep pipeline 2-deep (no hoist)
            khc = khn; kmc = kmn; klc = kln;
        }
    }
#pragma unroll
    for (int t = 0; t < 8; ++t)
#pragma unroll
        for (int r = 0; r < 4; ++r)
            S[quad * 4 + r][w * 128 + t * 16 + l15] = acc[t][r] * 8.0f;
    __syncthreads();

    // ---- phase 2: softmax (16 threads per row, 32 cols each) ----
    const int row = tid >> 4, c16 = tid & 15;
    const int cb = c16 * 32;
    float mx = -3.4e38f;
#pragma unroll 8
    for (int c = 0; c < 32; ++c) mx = fmaxf(mx, S[row][cb + c]);
    red[row][c16] = mx;
    __syncthreads();
    if (c16 == 0) {
        float m2 = red[row][0];
#pragma unroll
        for (int j = 1; j < 16; ++j) m2 = fmaxf(m2, red[row][j]);
        stat[row] = m2;
    }
    __syncthreads();
    mx = stat[row];
    float ev[32];
    float sum = 0.f;
#pragma unroll 8
    for (int c = 0; c < 32; ++c) {
        ev[c] = expf(S[row][cb + c] - mx);
        sum += ev[c];
    }
    red[row][c16] = sum;
    __syncthreads();
    if (c16 == 0) {
        float s2 = 0.f;
#pragma unroll
        for (int j = 0; j < 16; ++j) s2 += red[row][j];
        stat[row] = s2;
    }
    __syncthreads();                       // all S reads done -> overlay P
    const float den = stat[row];
    USH* const P0 = (USH*)&S[0][0];        // P hi plane
    USH* const P1 = P0 + 16 * 520;         // P mid plane
    USH* const P2 = P2buf;                 // P lo plane
#pragma unroll 8
    for (int c = 0; c < 32; ++c) {
        const float pr = ev[c] / den;      // divide, like numpy softmax
        USH hh, mm, ll;
        split3(pr, hh, mm, ll);
        P0[row * 520 + cb + c] = hh;
        P1[row * 520 + cb + c] = mm;
        P2[row * 520 + cb + c] = ll;
    }
    __syncthreads();

    // ---- phase 3: O = P V.  wave w covers n-tiles nt = w, w+4, ... ----
    const int nnt = hd >> 4;
    for (int nt = w; nt < nnt; nt += 4) {
        floatx4 o = zero;
        const int colg = h * hd + nt * 16 + l15;
        const size_t vb = (size_t)colg * Mc + b * SS;
#pragma unroll 2
        for (int ks = 0; ks < 16; ++ks) {
            const int ko = ks * 32 + quad * 8;
            const short8 ph = *(const short8*)&P0[l15 * 520 + ko];
            const short8 pm = *(const short8*)&P1[l15 * 520 + ko];
            const short8 pl = *(const short8*)&P2[l15 * 520 + ko];
            const short8 vh = *(const short8*)&VH[vb + ko];
            const short8 vm = *(const short8*)&VM[vb + ko];
            const short8 vl = *(const short8*)&VL[vb + ko];
            o = MFMA16(ph, vh, o);
            o = MFMA16(ph, vm, o);
            o = MFMA16(pm, vh, o);
            o = MFMA16(ph, vl, o);
            o = MFMA16(pl, vh, o);
            o = MFMA16(pm, vm, o);
        }
#pragma unroll
        for (int r = 0; r < 4; ++r) {
            const int orow = b * SS + q0 + quad * 4 + r;
            O[(size_t)orow * 768 + colg] = o[r];
        }
    }
}

// ---------------------------------------------------------------------------
// SLOW (R0) fused attention: Q,K f32 row-major; V f32 transposed [768][Mc].
// ---------------------------------------------------------------------------
__global__ __launch_bounds__(256) void attn_k(
    const float* __restrict__ Q, const float* __restrict__ Kp,
    const float* __restrict__ Vt, float* __restrict__ O,
    int H, int hd, int Mc)
{
    __shared__ __align__(16) float S[16][520];
    __shared__ __align__(16) USH P2buf[16 * 520];
    __shared__ float red[16][16];
    __shared__ float stat[16];

    const int tid  = threadIdx.x;
    const int lane = tid & 63;
    const int w    = tid >> 6;
    const int quad = lane >> 4, l15 = lane & 15;
    const int b = blockIdx.y / H;
    const int h = blockIdx.y - b * H;
    const int q0 = blockIdx.x * 16;

    const floatx4 zero = {0.f, 0.f, 0.f, 0.f};

    floatx4 acc[8];
#pragma unroll
    for (int t = 0; t < 8; ++t) acc[t] = zero;

    const size_t qbase = ((size_t)(b * SS + q0 + l15)) * DD + h * hd;
    const int nks = hd >> 5;
    for (int ks = 0; ks < nks; ++ks) {
        const int co = ks * 32 + quad * 8;
        float qv[8];
        *(float4*)&qv[0] = *(const float4*)(Q + qbase + co);
        *(float4*)&qv[4] = *(const float4*)(Q + qbase + co + 4);
        short8 qh, qm, ql;
        split3x8(qv, qh, qm, ql);
#pragma unroll
        for (int t = 0; t < 8; ++t) {
            const size_t kb = ((size_t)(b * SS + w * 128 + t * 16 + l15)) * DD + h * hd + co;
            float kv[8];
            *(float4*)&kv[0] = *(const float4*)(Kp + kb);
            *(float4*)&kv[4] = *(const float4*)(Kp + kb + 4);
            short8 kh, km, kl;
            split3x8(kv, kh, km, kl);
            acc[t] = MFMA16(qh, kh, acc[t]);
            acc[t] = MFMA16(qh, km, acc[t]);
            acc[t] = MFMA16(qm, kh, acc[t]);
            acc[t] = MFMA16(qh, kl, acc[t]);
            acc[t] = MFMA16(ql, kh, acc[t]);
            acc[t] = MFMA16(qm, km, acc[t]);
        }
    }
#pragma unroll
    for (int t = 0; t < 8; ++t)
#pragma unroll
        for (int r = 0; r < 4; ++r)
            S[quad * 4 + r][w * 128 + t * 16 + l15] = acc[t][r] * 8.0f;
    __syncthreads();

    const int row = tid >> 4, c16 = tid & 15;
    const int cb = c16 * 32;
    float mx = -3.4e38f;
#pragma unroll 8
    for (int c = 0; c < 32; ++c) mx = fmaxf(mx, S[row][cb + c]);
    red[row][c16] = mx;
    __syncthreads();
    if (c16 == 0) {
        float m2 = red[row][0];
#pragma unroll
        for (int j = 1; j < 16; ++j) m2 = fmaxf(m2, red[row][j]);
        stat[row] = m2;
    }
    __syncthreads();
    mx = stat[row];
    float ev[32];
    float sum = 0.f;
#pragma unroll 8
    for (int c = 0; c < 32; ++c) {
        ev[c] = expf(S[row][cb + c] - mx);
        sum += ev[c];
    }
    red[row][c16] = sum;
    __syncthreads();
    if (c16 == 0) {
        float s2 = 0.f;
#pragma unroll
        for (int j = 0; j < 16; ++j) s2 += red[row][j];
        stat[row] = s2;
    }
    __syncthreads();
    const float den = stat[row];
    USH* const P0 = (USH*)&S[0][0];
    USH* const P1 = P0 + 16 * 520;
    USH* const P2 = P2buf;
#pragma unroll 8
    for (int c = 0; c < 32; ++c) {
        const float pr = ev[c] / den;
        USH hh, mm, ll;
        split3(pr, hh, mm, ll);
        P0[row * 520 + cb + c] = hh;
        P1[row * 520 + cb + c] = mm;
        P2[row * 520 + cb + c] = ll;
    }
    __syncthreads();

    const int nnt = hd >> 4;
    for (int nt = w; nt < nnt; nt += 4) {
        floatx4 o = zero;
        const int colg = h * hd + nt * 16 + l15;
        const size_t vb = (size_t)colg * Mc + b * SS;
        for (int ks = 0; ks < 16; ++ks) {
            const int ko = ks * 32 + quad * 8;
            const short8 ph = *(const short8*)&P0[l15 * 520 + ko];
            const short8 pm = *(const short8*)&P1[l15 * 520 + ko];
            const short8 pl = *(const short8*)&P2[l15 * 520 + ko];
            float vv[8];
            *(float4*)&vv[0] = *(const float4*)(Vt + vb + ko);
            *(float4*)&vv[4] = *(const float4*)(Vt + vb + ko + 4);
            short8 vh, vm, vl;
            split3x8(vv, vh, vm, vl);
            o = MFMA16(ph, vh, o);
            o = MFMA16(ph, vm, o);
            o = MFMA16(pm, vh, o);
            o = MFMA16(ph, vl, o);
            o = MFMA16(pl, vh, o);
            o = MFMA16(pm, vm, o);
        }
#pragma unroll
        for (int r = 0; r < 4; ++r) {
            const int orow = b * SS + q0 + quad * 4 + r;
            O[(size_t)orow * 768 + colg] = o[r];
        }
    }
}

// ---------------------------------------------------------------------------
// Gate: x = x * softmax(x, row) + x, in-place f32. 1 block / row.
// ---------------------------------------------------------------------------
__global__ __launch_bounds__(256) void gate_k(float* __restrict__ X) {
    __shared__ float red[256];
    const int r = blockIdx.x, tid = threadIdx.x;
    const size_t base = (size_t)r * DD;
    float x[3];
#pragma unroll
    for (int j = 0; j < 3; ++j) x[j] = X[base + tid + j * 256];
    float mx = fmaxf(x[0], fmaxf(x[1], x[2]));
    red[tid] = mx;
    __syncthreads();
    for (int s = 128; s > 0; s >>= 1) {
        if (tid < s) red[tid] = fmaxf(red[tid], red[tid + s]);
        __syncthreads();
    }
    mx = red[0];
    __syncthreads();
    float e[3];
    float sum = 0.f;
#pragma unroll
    for (int j = 0; j < 3; ++j) { e[j] = expf(x[j] - mx); sum += e[j]; }
    red[tid] = sum;
    __syncthreads();
    for (int s = 128; s > 0; s >>= 1) {
        if (tid < s) red[tid] += red[tid + s];
        __syncthreads();
    }
    const float den = red[0];
#pragma unroll
    for (int j = 0; j < 3; ++j)
        X[base + tid + j * 256] = x[j] * (e[j] / den) + x[j];
}

// ---------------------------------------------------------------------------
// Final: es = text + F1 + F2 + F3 ;  out = es * softmax(es,row) + es  (f32)
// ---------------------------------------------------------------------------
__global__ __launch_bounds__(256) void final_k(
    const float* __restrict__ text,
    const float* __restrict__ F1, const float* __restrict__ F2,
    const float* __restrict__ F3, float* __restrict__ out)
{
    __shared__ float red[256];
    const int r = blockIdx.x, tid = threadIdx.x;
    const size_t base = (size_t)r * DD;
    float x[3];
#pragma unroll
    for (int j = 0; j < 3; ++j) {
        const int c = tid + j * 256;
        x[j] = ((text[base + c] + F1[base + c]) + F2[base + c]) + F3[base + c];
    }
    float mx = fmaxf(x[0], fmaxf(x[1], x[2]));
    red[tid] = mx;
    __syncthreads();
    for (int s = 128; s > 0; s >>= 1) {
        if (tid < s) red[tid] = fmaxf(red[tid], red[tid + s]);
        __syncthreads();
    }
    mx = red[0];
    __syncthreads();
    float e[3];
    float sum = 0.f;
#pragma unroll
    for (int j = 0; j < 3; ++j) { e[j] = expf(x[j] - mx); sum += e[j]; }
    red[tid] = sum;
    __syncthreads();
    for (int s = 128; s > 0; s >>= 1) {
        if (tid < s) red[tid] += red[tid + s];
        __syncthreads();
    }
    const float den = red[0];
#pragma unroll
    for (int j = 0; j < 3; ++j) {
        const int c = tid + j * 256;
        out[base + c] = x[j] * (e[j] / den) + x[j];
    }
}

// ===========================================================================
// Host orchestration — dual path.
// ===========================================================================
extern "C" void kernel_launch(void* const* d_in, const int* in_sizes, int n_in,
                              void* d_out, int out_size, void* d_ws, size_t ws_size,
                              hipStream_t stream)
{
    (void)in_sizes; (void)n_in; (void)out_size;

    const float* text    = (const float*)d_in[0];
    const int*   vis_ids = (const int*)d_in[1];
    const int*   ac_ids  = (const int*)d_in[2];
    const float* vis_tab = (const float*)d_in[3];
    const float* ac_tab  = (const float*)d_in[4];
    const float* hv_wq = (const float*)d_in[5],  *hv_bq = (const float*)d_in[6];
    const float* hv_wk = (const float*)d_in[7],  *hv_bk = (const float*)d_in[8];
    const float* hv_wv = (const float*)d_in[9],  *hv_bv = (const float*)d_in[10];
    const float* ha_wq = (const float*)d_in[11], *ha_bq = (const float*)d_in[12];
    const float* ha_wk = (const float*)d_in[13], *ha_bk = (const float*)d_in[14];
    const float* ha_wv = (const float*)d_in[15], *ha_bv = (const float*)d_in[16];
    const float* ht_wq = (const float*)d_in[17], *ht_bq = (const float*)d_in[18];
    const float* ht_wk = (const float*)d_in[19], *ht_bk = (const float*)d_in[20];
    const float* ht_wv = (const float*)d_in[21], *ht_bv = (const float*)d_in[22];
    const float* ht_fcw = (const float*)d_in[23], *ht_fcb = (const float*)d_in[24];
    const float* ffn_w1 = (const float*)d_in[25], *ffn_b1 = (const float*)d_in[26];
    const float* ffn_w2 = (const float*)d_in[27], *ffn_b2 = (const float*)d_in[28];
    const float* cat_w  = (const float*)d_in[29], *cat_b  = (const float*)d_in[30];

    // ---------------- workspace sizing ----------------
    // ws in [227.3MB (R2 fast fit proven), 276MB).  fast@8192 = 227.3MB.
    const size_t SQ   = (size_t)768 * 768;                     // USH per plane
    const size_t WUSH = 3 * (12 * SQ + (size_t)768 * 1536);    // 24,772,608 USH
    const size_t TABF = (size_t)512 * 384 * 2;                 // floats
    int Mc = 0, fast = 0;
    for (int cand = MM; cand >= 512; cand >>= 1) {
        const size_t nf = WUSH * sizeof(USH) + TABF * 4 + (size_t)cand * 768 * 28;
        const size_t ns = WUSH * sizeof(USH) + (size_t)cand * 768 * 24;
        if (nf <= ws_size) { Mc = cand; fast = 1; break; }
        if (ns <= ws_size) { Mc = cand; fast = 0; break; }
    }
    if (Mc == 0) return;    // diagnostic: wrong output, not a fault
    const int nchunk = MM / Mc;
    const int chB    = Mc / SS;

    USH* p = (USH*)d_ws;
    USH *wt0[13], *wt1[13], *wt2[13];
    for (int i = 0; i < 13; ++i) {
        const size_t sz = (i == 12) ? (size_t)768 * 1536 : SQ;
        wt0[i] = p; p += sz;
        wt1[i] = p; p += sz;
        wt2[i] = p; p += sz;
    }

    // weight indices: 0 hv_wq 1 hv_wk 2 hv_wv 3 ha_wq 4 ha_wk 5 ha_wv
    //                 6 ht_wq 7 ht_wk 8 ht_wv 9 ht_fcw 10 ffn_w1 11 ffn_w2 12 cat_w
    TransArgs ta;
    const float* tin[13] = {hv_wq, hv_wk, hv_wv, ha_wq, ha_wk, ha_wv,
                            ht_wq, ht_wk, ht_wv, ht_fcw, ffn_w1, ffn_w2, cat_w};
    for (int i = 0; i < 13; ++i) {
        ta.in[i] = tin[i]; ta.o0[i] = wt0[i]; ta.o1[i] = wt1[i]; ta.o2[i] = wt2[i];
        ta.R[i] = (i == 12) ? 1536 : 768;
    }
    trans_k<<<dim3(48, 24, 13), 256, 0, stream>>>(ta);

    const size_t PSZ = (size_t)Mc * 768;       // elements per plane
    const dim3 gg(Mc / 128, DD / 128), gb(256);
    const int ropeg = Mc * 384 / 256;
    const float* NULF = nullptr;
    USH* const NUSH = nullptr;

    if (fast) {
        // layout: weights | tab | A,B,C,F f32 | KH KM KL VH VM VL bf16
        float* tab = (float*)p;
        float* fp  = tab + TABF;
        float *A_ = fp + 0 * PSZ, *B_ = fp + 1 * PSZ;
        float *C_ = fp + 2 * PSZ, *F_ = fp + 3 * PSZ;
        USH* KH = (USH*)(fp + 4 * PSZ);
        USH* KM = KH + PSZ;  USH* KL = KM + PSZ;
        USH* VH = KL + PSZ;  USH* VM = VH + PSZ;  USH* VL = VM + PSZ;

        tab_k<<<(512 * 384) / 256, 256, 0, stream>>>(tab);

// plain GEMM (f32 out)
#define GE(A0P, A1P, WI, LDB, BIAS, CP, KK, ACT) \
    gemm_k<<<gg, gb, 0, stream>>>(A0P, A1P, NUSH, NUSH, NUSH, 768, \
        wt0[WI], wt1[WI], wt2[WI], LDB, (size_t)0, BIAS, 1.0f, CP, 768, \
        NUSH, NUSH, NUSH, tab, KK, ACT, 0, 0, Mc)
// Q GEMM: rope fused, f32 out
#define GQ(A0P, WI, BIAS, CP) \
    gemm_k<<<gg, gb, 0, stream>>>(A0P, NULF, NUSH, NUSH, NUSH, 768, \
        wt0[WI], wt1[WI], wt2[WI], 768, (size_t)0, BIAS, 1.0f, CP, 768, \
        NUSH, NUSH, NUSH, tab, 768, 0, 0, 1, Mc)
// K GEMM: rope fused, row-major 3-plane bf16 out
#define GK(A0P, WI, BIAS) \
    gemm_k<<<gg, gb, 0, stream>>>(A0P, NULF, NUSH, NUSH, NUSH, 768, \
        wt0[WI], wt1[WI], wt2[WI], 768, (size_t)0, BIAS, 1.0f, (float*)nullptr, 768, \
        KH, KM, KL, tab, 768, 0, 3, 1, Mc)
// V GEMM: transposed 3-plane bf16 out (LDS-coalesced epilogue)
#define GV(A0P, WI, BIAS) \
    gemm_k<<<gg, gb, 0, stream>>>(A0P, NULF, NUSH, NUSH, NUSH, 768, \
        wt0[WI], wt1[WI], wt2[WI], 768, (size_t)0, BIAS, 1.0f, (float*)nullptr, 768, \
        VH, VM, VL, tab, 768, 0, 1, 0, Mc)
// score GEMM: S = (Q @ K[b]^T)*8 -> outc [Mc][512]
#define SGEMM(QP) \
    gemm_k<<<dim3(Mc / 128, 4), gb, 0, stream>>>(QP, NULF, NUSH, NUSH, NUSH, 768, \
        KH, KM, KL, 768, (size_t)512 * 768, NULF, 8.0f, outc, 512, \
        NUSH, NUSH, NUSH, tab, 768, 0, 0, 0, Mc)
// row softmax -> P planes overwrite dead K planes (stride 512)
#define SMAX() smax_k<<<Mc, 256, 0, stream>>>(outc, KH, KM, KL)
// PV GEMM: O = P @ V[b] -> f32 [Mc][768]
#define PVG(OP) \
    gemm_k<<<dim3(Mc / 128, 6), gb, 0, stream>>>(NULF, NULF, KH, KM, KL, 512, \
        VH, VM, VL, Mc, (size_t)512, NULF, 1.0f, OP, 768, \
        NUSH, NUSH, NUSH, tab, 512, 0, 0, 0, Mc)
#define ATTNF(QP, OP, HH, HD) \
    attn_fast_k<<<dim3(SS / 16, chB * (HH)), 256, 0, stream>>>(QP, KH, KM, KL, \
                                                  VH, VM, VL, OP, HH, HD, Mc)
#define GATE(XP) gate_k<<<Mc, 256, 0, stream>>>(XP)

        for (int c = 0; c < nchunk; ++c) {
            const float* tx = text + (size_t)c * PSZ;
            const int* vi = vis_ids + (size_t)c * Mc;
            const int* ai = ac_ids  + (size_t)c * Mc;
            float* outc = (float*)d_out + (size_t)c * PSZ;   // scratch till final

            gather_k<<<Mc * 192 / 256, 256, 0, stream>>>(vi, vis_tab, A_);  // Ev
            gather_k<<<Mc * 192 / 256, 256, 0, stream>>>(ai, ac_tab, B_);   // Ea

            // ---- v1 = hv(text, Ev) -> F_ ----
            GQ(tx, 0, hv_bq, C_);
            GK(A_, 1, hv_bk);  GV(A_, 2, hv_bv);
            SGEMM(C_); SMAX(); PVG(F_);                      // (Ev dead)

            // ---- a1 = ha(text, Ea) -> A_ ----
            GQ(tx, 3, ha_bq, C_);
            GK(B_, 4, ha_bk);  GV(B_, 5, ha_bv);
            SGEMM(C_); SMAX(); PVG(A_);                      // (Ea dead)

            // ---- v2 = hv(v1, a1) -> C_ ----
            GQ(F_, 0, hv_bq, C_);
            GK(A_, 1, hv_bk);  GV(A_, 2, hv_bv);
            SGEMM(C_); SMAX(); PVG(C_);                      // C_ (Q) dead after SGEMM

            // ---- a2 = ha(a1, v1) -> B_ ----
            GQ(A_, 3, ha_bq, B_);
            GK(F_, 4, ha_bk);  GV(F_, 5, ha_bv);
            SGEMM(B_); SMAX(); PVG(B_);                      // B_ (Q) dead after SGEMM

            // ---- F1 = ffn(gate(cat(v1,a1) @ cat_w)) -> A_ ----
            GE(F_, A_, 12, 1536, cat_b, outc, 1536, 0);      // T1
            GATE(outc);
            GE(outc, NULF, 10, 768, ffn_b1, F_, 768, 1);     // H (v1 dead)
            GE(F_, NULF, 11, 768, ffn_b2, A_, 768, 0);       // F1 -> A_ (a1 dead)

            // ---- F2 = ffn(gate(cat(v2,a2) @ cat_w)) -> C_ ----
            GE(C_, B_, 12, 1536, cat_b, outc, 1536, 0);      // T2
            GATE(outc);
            GE(outc, NULF, 10, 768, ffn_b1, F_, 768, 1);     // H
            GE(F_, NULF, 11, 768, ffn_b2, C_, 768, 0);       // F2 -> C_ (v2 dead)

            // ---- F3 = ffn(gate(fc(ht(F1, text)))) -> F_ ----
            GQ(A_, 6, ht_bq, B_);                            // Q <- F1 (a2 dead)
            GK(tx, 7, ht_bk);  GV(tx, 8, ht_bv);
            ATTNF(B_, B_, 8, 96);                            // AO aliases Q
            GE(B_, NULF, 9, 768, ht_fcb, F_, 768, 0);        // fc
            GATE(F_);
            GE(F_, NULF, 10, 768, ffn_b1, B_, 768, 1);       // H
            GE(B_, NULF, 11, 768, ffn_b2, F_, 768, 0);       // F3

            final_k<<<Mc, 256, 0, stream>>>(tx, A_, C_, F_, outc);
        }
#undef GE
#undef GQ
#undef GK
#undef GV
#undef SGEMM
#undef SMAX
#undef PVG
#undef ATTNF
#undef GATE
    } else {
        // -------- SLOW path: exact R0 (6 f32 planes, on-the-fly splits) ------
        float* fp = (float*)p;
        float *A_ = fp + 0 * PSZ, *B_ = fp + 1 * PSZ, *C_ = fp + 2 * PSZ;
        float *D_ = fp + 3 * PSZ, *E_ = fp + 4 * PSZ, *F_ = fp + 5 * PSZ;

#define GEMM(A0P, A1P, WI, LDB, BIAS, CP, KK, ACT, TOUT) \
    gemm_k<<<gg, gb, 0, stream>>>(A0P, A1P, NUSH, NUSH, NUSH, 768, \
        wt0[WI], wt1[WI], wt2[WI], LDB, (size_t)0, BIAS, 1.0f, CP, 768, \
        NUSH, NUSH, NUSH, NULF, KK, ACT, TOUT, 0, Mc)
#define ROPE(XP) rope_k<<<ropeg, 256, 0, stream>>>(XP)
#define ATTN(QP, KP, VP, OP, HH, HD) \
    attn_k<<<dim3(SS / 16, chB * (HH)), 256, 0, stream>>>(QP, KP, VP, OP, HH, HD, Mc)
#define GATE(XP) gate_k<<<Mc, 256, 0, stream>>>(XP)

        for (int c = 0; c < nchunk; ++c) {
            const float* tx = text + (size_t)c * PSZ;
            const int* vi = vis_ids + (size_t)c * Mc;
            const int* ai = ac_ids  + (size_t)c * Mc;
            float* outc = (float*)d_out + (size_t)c * PSZ;

            gather_k<<<Mc * 192 / 256, 256, 0, stream>>>(vi, vis_tab, A_);
            gather_k<<<Mc * 192 / 256, 256, 0, stream>>>(ai, ac_tab, B_);

            GEMM(tx, NULF, 0, 768, hv_bq, C_, 768, 0, 0);
            GEMM(A_, NULF, 1, 768, hv_bk, D_, 768, 0, 0);
            GEMM(A_, NULF, 2, 768, hv_bv, E_, 768, 0, 2);
            ROPE(C_); ROPE(D_);
            ATTN(C_, D_, E_, F_, 1, 768);

            GEMM(tx, NULF, 3, 768, ha_bq, C_, 768, 0, 0);
            GEMM(B_, NULF, 4, 768, ha_bk, D_, 768, 0, 0);
            GEMM(B_, NULF, 5, 768, ha_bv, E_, 768, 0, 2);
            ROPE(C_); ROPE(D_);
            ATTN(C_, D_, E_, A_, 1, 768);

            GEMM(F_, NULF, 0, 768, hv_bq, C_, 768, 0, 0);
            GEMM(A_, NULF, 1, 768, hv_bk, D_, 768, 0, 0);
            GEMM(A_, NULF, 2, 768, hv_bv, E_, 768, 0, 2);
            ROPE(C_); ROPE(D_);
            ATTN(C_, D_, E_, C_, 1, 768);

            GEMM(A_, NULF, 3, 768, ha_bq, B_, 768, 0, 0);
            GEMM(F_, NULF, 4, 768, ha_bk, D_, 768, 0, 0);
            GEMM(F_, NULF, 5, 768, ha_bv, E_, 768, 0, 2);
            ROPE(B_); ROPE(D_);
            ATTN(B_, D_, E_, B_, 1, 768);

            GEMM(F_, A_, 12, 1536, cat_b, D_, 1536, 0, 0);
            GATE(D_);
            GEMM(D_, NULF, 10, 768, ffn_b1, E_, 768, 1, 0);
            GEMM(E_, NULF, 11, 768, ffn_b2, F_, 768, 0, 0);

            GEMM(C_, B_, 12, 1536, cat_b, A_, 1536, 0, 0);
            GATE(A_);
            GEMM(A_, NULF, 10, 768, ffn_b1, C_, 768, 1, 0);
            GEMM(C_, NULF, 11, 768, ffn_b2, B_, 768, 0, 0);

            GEMM(F_, NULF, 6, 768, ht_bq, C_, 768, 0, 0);
            GEMM(tx, NULF, 7, 768, ht_bk, D_, 768, 0, 0);
            GEMM(tx, NULF, 8, 768, ht_bv, E_, 768, 0, 2);
            ROPE(C_); ROPE(D_);
            ATTN(C_, D_, E_, C_, 8, 96);
            GEMM(C_, NULF, 9, 768, ht_fcb, A_, 768, 0, 0);
            GATE(A_);
            GEMM(A_, NULF, 10, 768, ffn_b1, C_, 768, 1, 0);
            GEMM(C_, NULF, 11, 768, ffn_b2, D_, 768, 0, 0);

            final_k<<<Mc, 256, 0, stream>>>(tx, F_, B_, D_, outc);
        }
#undef GEMM
#undef ROPE
#undef ATTN
#undef GATE
    }
}

// Round 7
// 6287.980 us; speedup vs baseline: 1.1868x; 1.0285x over previous
//
#include <hip/hip_runtime.h>
#include <stdint.h>
#include <math.h>

// ============================================================================
// MCFNet on MI355X (gfx950).  INPUTS FLOAT32; OUTPUT FLOAT32.
// Numerics: all tensors stored f32.  Every matmul runs on MFMA bf16 with
// 3-plane splits (x = h + m + l, rep error ~2^-27) and 6 passes
// (hh, hm, mh, hl, lh, mm).  Weights pre-split into 3 transposed bf16 planes.
//
// R7 (on the R6 skeleton; gemm_k staging only):
//  - B-plane staging (all GEMMs) and pre-split-A staging (PV GEMM) now use
//    __builtin_amdgcn_global_load_lds width=16 (async DMA, no VGPR round
//    trip, no ds_write).  Per wave per plane: 2 issues of 1KiB; LDS bytes
//    land in exactly the old layout (dest USH w*1024+i*512+lane*8 == row
//    32w+16i+(lane>>2), col (lane&3)*8).  __syncthreads drains vmcnt.
//  - A-f32 path keeps in-kernel split3 reg-staging (conversion needed).
//  - Everything else (R6 GEMM-decomposed hd=768 attention, fused H=8 attn,
//    rope-fused epilogues, host schedule) byte-identical.
// ============================================================================

typedef unsigned short USH;
typedef __attribute__((ext_vector_type(8))) short short8;
typedef __attribute__((ext_vector_type(4))) float floatx4;

#define MFMA16(a, b, c) __builtin_amdgcn_mfma_f32_16x16x32_bf16((a), (b), (c), 0, 0, 0)

static constexpr int NB = 32;          // batch
static constexpr int SS = 512;         // seq len
static constexpr int DD = 768;         // model dim
static constexpr int MM = NB * SS;     // 16384 rows

__device__ __forceinline__ float bf2f(USH h) {
    return __uint_as_float(((unsigned)h) << 16);
}
__device__ __forceinline__ USH f2bf(float x) {          // round-to-nearest-even
    unsigned u = __float_as_uint(x);
    return (USH)((u + 0x7fffu + ((u >> 16) & 1u)) >> 16);
}
// 3-plane split: x = h + m + l + err, |err| <= 2^-27 |x| (residuals exact).
__device__ __forceinline__ void split3(float x, USH &h, USH &m, USH &l) {
    h = f2bf(x);
    const float r1 = x - bf2f(h);
    m = f2bf(r1);
    const float r2 = r1 - bf2f(m);
    l = f2bf(r2);
}
__device__ __forceinline__ void split3x8(const float* v, short8 &H, short8 &M, short8 &L) {
#pragma unroll
    for (int j = 0; j < 8; ++j) {
        USH h, m, l;
        split3(v[j], h, m, l);
        H[j] = (short)h; M[j] = (short)m; L[j] = (short)l;
    }
}
__device__ __forceinline__ uint2 pk4(USH a, USH b, USH c, USH d) {
    uint2 r;
    r.x = (unsigned)a | ((unsigned)b << 16);
    r.y = (unsigned)c | ((unsigned)d << 16);
    return r;
}
// Async global->LDS 16B copy: dest = lds base (wave-uniform) + lane*16.
__device__ __forceinline__ void gload16(const USH* g, USH* l) {
    __builtin_amdgcn_global_load_lds(
        (const __attribute__((address_space(1))) unsigned int*)g,
        (__attribute__((address_space(3))) unsigned int*)l,
        16, 0, 0);
}

// ---------------------------------------------------------------------------
// Weight transpose+split: f32 [R][768] -> 3 bf16 planes [768][R].
// ---------------------------------------------------------------------------
struct TransArgs {
    const float* in[13];
    USH* o0[13]; USH* o1[13]; USH* o2[13];
    int R[13];
};

__global__ __launch_bounds__(256) void trans_k(TransArgs a) {
    const int mi = blockIdx.z;
    const float* __restrict__ in = a.in[mi];
    USH* __restrict__ o0 = a.o0[mi];
    USH* __restrict__ o1 = a.o1[mi];
    USH* __restrict__ o2 = a.o2[mi];
    const int R = a.R[mi];
    const int bx = blockIdx.x, by = blockIdx.y;
    if (bx * 32 >= R) return;
    __shared__ float t[32][33];
    const int tx = threadIdx.x & 31, ty = threadIdx.x >> 5;   // 32 x 8
#pragma unroll
    for (int i = 0; i < 4; ++i)
        t[ty + i * 8][tx] = in[(size_t)(bx * 32 + ty + i * 8) * 768 + by * 32 + tx];
    __syncthreads();
#pragma unroll
    for (int i = 0; i < 4; ++i) {
        USH h, m, l;
        split3(t[tx][ty + i * 8], h, m, l);
        const size_t o = (size_t)(by * 32 + ty + i * 8) * R + bx * 32 + tx;
        o0[o] = h; o1[o] = m; o2[o] = l;
    }
}

// ---------------------------------------------------------------------------
// Embedding gather: dst[m,:] = table[ids[m],:]  (f32 copy)
// ---------------------------------------------------------------------------
__global__ __launch_bounds__(256) void gather_k(const int* __restrict__ ids,
                                                const float* __restrict__ table,
                                                float* __restrict__ dst) {
    const int g  = blockIdx.x * 256 + threadIdx.x;
    const int m  = g / 192;
    const int c4 = (g - m * 192) * 4;
    const int id = ids[m];
    *(float4*)(dst + (size_t)m * DD + c4) =
        *(const float4*)(table + (size_t)id * DD + c4);
}

// ---------------------------------------------------------------------------
// RoPE cos/sin table: tab[s][i] = {cos,sin}(s * theta_i), 512 x 384.
// ---------------------------------------------------------------------------
__global__ __launch_bounds__(256) void tab_k(float* __restrict__ tab) {
    const int p = blockIdx.x * 256 + threadIdx.x;
    const int s = p / 384;
    const int i = p - s * 384;
    const float ef = (-2.0f * (float)i) / 768.0f;
    const float th = (float)pow(10000.0, (double)ef);
    const float ang = (float)s * th;
    float sn, cs;
    sincosf(ang, &sn, &cs);
    tab[2 * p]     = cs;
    tab[2 * p + 1] = sn;
}

// Slow-path RoPE (R0, pow per thread), in-place f32.
__global__ __launch_bounds__(256) void rope_k(float* __restrict__ X) {
    const int p = blockIdx.x * 256 + threadIdx.x;
    const int m = p / 384;
    const int i = p - m * 384;
    const int s = m & (SS - 1);
    const float ef = (-2.0f * (float)i) / 768.0f;
    const float th = (float)pow(10000.0, (double)ef);
    const float ang = (float)s * th;
    float sn, cs;
    sincosf(ang, &sn, &cs);
    float2 x = *(float2*)(X + (size_t)m * DD + 2 * i);
    float2 y;
    y.x = x.x * cs - x.y * sn;
    y.y = x.y * cs + x.x * sn;
    *(float2*)(X + (size_t)m * DD + 2 * i) = y;
}

// ---------------------------------------------------------------------------
// GEMM: C[Mc,N] = A[Mc,K] @ W[K,N] + bias.
// A: f32 (A0/A1 concat halves, stride 768, split3 in-kernel, reg-staged) OR
//    pre-split 3 bf16 planes AP0/1/2 stride lda (PV path — global_load_lds).
// B: 3 bf16 planes [N][K] stride ldb, staged via global_load_lds (16B);
//    bofs != 0 adds (gm0/512)*bofs to plane base (batched attention operand).
// Epilogue: x = acc*scale + bias; act 1 = SiLU; rope 1 = fused RoPE (tab).
// tout: 0 f32 C[row*ldc+col]; 1 transposed 3-plane bf16 via LDS (V^T);
//       2 transposed f32 (slow path V^T); 3 row-major 3-plane bf16 (K planes).
// XCD-chunked bijective block swizzle (grid %8 == 0).
// ---------------------------------------------------------------------------
__global__ __launch_bounds__(256) void gemm_k(
    const float* __restrict__ A0, const float* __restrict__ A1,
    const USH* __restrict__ AP0, const USH* __restrict__ AP1,
    const USH* __restrict__ AP2, int lda,
    const USH* __restrict__ B0, const USH* __restrict__ B1, const USH* __restrict__ B2,
    int ldb, size_t bofs,
    const float* __restrict__ bias, float scale,
    float* __restrict__ C, int ldc,
    USH* __restrict__ S0p, USH* __restrict__ S1p, USH* __restrict__ S2p,
    const float* __restrict__ tab,
    int K, int act, int tout, int rope, int Mc)
{
    __shared__ __align__(16) USH smem[24576];
    USH* const sA0 = smem;
    USH* const sA1 = smem + 4096;
    USH* const sA2 = smem + 8192;
    USH* const sB0 = smem + 12288;
    USH* const sB1 = smem + 16384;
    USH* const sB2 = smem + 20480;

    const int tid  = threadIdx.x;
    const int lane = tid & 63;
    const int w    = tid >> 6;
    const int quad = lane >> 4, l15 = lane & 15;
    const int wm = (w >> 1) * 64, wn = (w & 1) * 64;

    // XCD-chunked bijective swizzle: consecutive work-ids share an XCD's L2.
    const int nbx = gridDim.x;
    const int tot = nbx * (int)gridDim.y;
    int bid = blockIdx.y * nbx + blockIdx.x;
    if ((tot & 7) == 0) bid = (bid & 7) * (tot >> 3) + (bid >> 3);
    const int byy = bid / nbx;
    const int gm0 = (bid - byy * nbx) * 128, gn0 = byy * 128;

    // batched per-b B operand (attention score / PV GEMMs)
    const USH* __restrict__ Bp0 = B0;
    const USH* __restrict__ Bp1 = B1;
    const USH* __restrict__ Bp2 = B2;
    if (bofs) {
        const size_t ad = (size_t)(gm0 >> 9) * bofs;
        Bp0 += ad; Bp1 += ad; Bp2 += ad;
    }

    // global_load_lds staging geometry: wave w stages bytes [2048w, 2048w+2048)
    // of each 8192B plane via 2 issues; lane's 16B lands at base + lane*16,
    // i.e. row 32w+16i+(lane>>2), col (lane&3)*8  (identical to old layout).
    const int srow = 32 * w + (lane >> 2);
    const int scol = (lane & 3) * 8;
    USH* const dB0 = sB0 + w * 1024;
    USH* const dB1 = sB1 + w * 1024;
    USH* const dB2 = sB2 + w * 1024;
    USH* const dA0 = sA0 + w * 1024;
    USH* const dA1 = sA1 + w * 1024;
    USH* const dA2 = sA2 + w * 1024;

    const floatx4 zero = {0.f, 0.f, 0.f, 0.f};
    floatx4 acc[4][4];
#pragma unroll
    for (int i = 0; i < 4; ++i)
#pragma unroll
        for (int j = 0; j < 4; ++j) acc[i][j] = zero;

    for (int k0 = 0; k0 < K; k0 += 32) {
        // ---- B staging: async DMA, 2 x 1KiB per wave per plane ----
        {
            const size_t bo = (size_t)(gn0 + srow) * ldb + k0 + scol;
            const size_t b16 = (size_t)16 * ldb;
            gload16(Bp0 + bo, dB0);
            gload16(Bp0 + bo + b16, dB0 + 512);
            gload16(Bp1 + bo, dB1);
            gload16(Bp1 + bo + b16, dB1 + 512);
            gload16(Bp2 + bo, dB2);
            gload16(Bp2 + bo + b16, dB2 + 512);
        }
        if (AP0) {
            // ---- A staging: pre-split planes, async DMA (PV path) ----
            const size_t ao = (size_t)(gm0 + srow) * lda + k0 + scol;
            const size_t a16 = (size_t)16 * lda;
            gload16(AP0 + ao, dA0);
            gload16(AP0 + ao + a16, dA0 + 512);
            gload16(AP1 + ao, dA1);
            gload16(AP1 + ao + a16, dA1 + 512);
            gload16(AP2 + ao, dA2);
            gload16(AP2 + ao + a16, dA2 + 512);
        } else {
            // ---- A staging: f32 -> split3 -> 3 planes; 4 float4/thread ----
            const float* __restrict__ A = (k0 < 768) ? A0 : A1;
            const int kof = (k0 < 768) ? k0 : (k0 - 768);
#pragma unroll
            for (int u = 0; u < 4; ++u) {
                const int idx = tid + u * 256;           // [0,1024)
                const int r = idx >> 3, c = (idx & 7) * 4;
                const float4 v = *(const float4*)(A + (size_t)(gm0 + r) * 768 + kof + c);
                USH h[4], m[4], l[4];
                split3(v.x, h[0], m[0], l[0]);
                split3(v.y, h[1], m[1], l[1]);
                split3(v.z, h[2], m[2], l[2]);
                split3(v.w, h[3], m[3], l[3]);
                *(uint2*)&sA0[r * 32 + c] = pk4(h[0], h[1], h[2], h[3]);
                *(uint2*)&sA1[r * 32 + c] = pk4(m[0], m[1], m[2], m[3]);
                *(uint2*)&sA2[r * 32 + c] = pk4(l[0], l[1], l[2], l[3]);
            }
        }
        __syncthreads();   // drains vmcnt (DMA) + lgkm (ds_write) before reads

        short8 a0[4], a1f[4], a2[4], b0[4], b1f[4], b2[4];
#pragma unroll
        for (int t = 0; t < 4; ++t) {
            const int ao = (wm + t * 16 + l15) * 32 + quad * 8;
            const int bo = (wn + t * 16 + l15) * 32 + quad * 8;
            a0[t]  = *(const short8*)&sA0[ao];
            a1f[t] = *(const short8*)&sA1[ao];
            a2[t]  = *(const short8*)&sA2[ao];
            b0[t]  = *(const short8*)&sB0[bo];
            b1f[t] = *(const short8*)&sB1[bo];
            b2[t]  = *(const short8*)&sB2[bo];
        }
        // 6 passes: hh, hm, mh, hl, lh, mm
#pragma unroll
        for (int i = 0; i < 4; ++i)
#pragma unroll
            for (int j = 0; j < 4; ++j) acc[i][j] = MFMA16(a0[i],  b0[j],  acc[i][j]);
#pragma unroll
        for (int i = 0; i < 4; ++i)
#pragma unroll
            for (int j = 0; j < 4; ++j) acc[i][j] = MFMA16(a0[i],  b1f[j], acc[i][j]);
#pragma unroll
        for (int i = 0; i < 4; ++i)
#pragma unroll
            for (int j = 0; j < 4; ++j) acc[i][j] = MFMA16(a1f[i], b0[j],  acc[i][j]);
#pragma unroll
        for (int i = 0; i < 4; ++i)
#pragma unroll
            for (int j = 0; j < 4; ++j) acc[i][j] = MFMA16(a0[i],  b2[j],  acc[i][j]);
#pragma unroll
        for (int i = 0; i < 4; ++i)
#pragma unroll
            for (int j = 0; j < 4; ++j) acc[i][j] = MFMA16(a2[i],  b0[j],  acc[i][j]);
#pragma unroll
        for (int i = 0; i < 4; ++i)
#pragma unroll
            for (int j = 0; j < 4; ++j) acc[i][j] = MFMA16(a1f[i], b1f[j], acc[i][j]);
        __syncthreads();
    }

    // ---- epilogue ----
    if (tout == 1) {
        // V^T planes via LDS transpose -> coalesced short8 stores.
        USH* const sT = smem;                       // 128*144 = 18432 USH
#pragma unroll
        for (int p = 0; p < 3; ++p) {
            __syncthreads();
#pragma unroll
            for (int j = 0; j < 4; ++j) {
                const int col = gn0 + wn + j * 16 + l15;
                const int cl  = wn + j * 16 + l15;
                const float bv = bias ? bias[col] : 0.0f;
#pragma unroll
                for (int i = 0; i < 4; ++i) {
#pragma unroll
                    for (int r = 0; r < 4; ++r) {
                        const int rl = wm + i * 16 + quad * 4 + r;
                        USH h, m, l;
                        split3(acc[i][j][r] * scale + bv, h, m, l);
                        sT[cl * 144 + rl] = (p == 0) ? h : ((p == 1) ? m : l);
                    }
                }
            }
            __syncthreads();
            USH* const dst = (p == 0) ? S0p : ((p == 1) ? S1p : S2p);
#pragma unroll
            for (int u = 0; u < 8; ++u) {
                const int cc = u * 256 + tid;       // [0, 2048)
                const int cl = cc >> 4, off = (cc & 15) * 8;
                *(short8*)(dst + (size_t)(gn0 + cl) * Mc + gm0 + off) =
                    *(const short8*)&sT[cl * 144 + off];
            }
        }
        return;
    }

#pragma unroll
    for (int j = 0; j < 4; ++j) {
        const int col = gn0 + wn + j * 16 + l15;
        const float bv = bias ? bias[col] : 0.0f;
#pragma unroll
        for (int i = 0; i < 4; ++i) {
#pragma unroll
            for (int r = 0; r < 4; ++r) {
                const int row = gm0 + wm + i * 16 + quad * 4 + r;
                float x = acc[i][j][r] * scale + bv;
                if (act == 1) {
                    const float s = 1.0f / (1.0f + expf(-x));   // sigmoid then mul
                    x = x * s;
                }
                if (rope) {
                    // partner lane holds col^1, same row; same math as rope_k.
                    const float px = __shfl_xor(x, 1, 64);
                    const float2 t = *(const float2*)(tab +
                        2 * ((row & (SS - 1)) * 384 + (col >> 1)));
                    x = (col & 1) ? (x * t.x + px * t.y)
                                  : (x * t.x - px * t.y);
                }
                if (tout == 3) {
                    USH h, m, l;
                    split3(x, h, m, l);
                    const size_t o = (size_t)row * 768 + col;
                    S0p[o] = h; S1p[o] = m; S2p[o] = l;
                } else if (tout == 2) {
                    C[(size_t)col * Mc + row] = x;
                } else {
                    C[(size_t)row * ldc + col] = x;
                }
            }
        }
    }
}

// ---------------------------------------------------------------------------
// Row softmax + split3: S f32 [rows][512] -> P 3 bf16 planes [rows][512].
// One block per row; max exact (fmax tree), sum tree (~1ulp vs serial).
// ---------------------------------------------------------------------------
__global__ __launch_bounds__(256) void smax_k(
    const float* __restrict__ S,
    USH* __restrict__ P0, USH* __restrict__ P1, USH* __restrict__ P2)
{
    __shared__ float red[256];
    const int row = blockIdx.x, tid = threadIdx.x;
    const size_t base = (size_t)row * 512;
    const float a = S[base + tid];
    const float b = S[base + 256 + tid];
    red[tid] = fmaxf(a, b);
    __syncthreads();
    for (int s = 128; s > 0; s >>= 1) {
        if (tid < s) red[tid] = fmaxf(red[tid], red[tid + s]);
        __syncthreads();
    }
    const float mx = red[0];
    __syncthreads();
    const float e0 = expf(a - mx);
    const float e1 = expf(b - mx);
    red[tid] = e0 + e1;
    __syncthreads();
    for (int s = 128; s > 0; s >>= 1) {
        if (tid < s) red[tid] += red[tid + s];
        __syncthreads();
    }
    const float den = red[0];
    USH h, m, l;
    split3(e0 / den, h, m, l);
    P0[base + tid] = h; P1[base + tid] = m; P2[base + tid] = l;
    split3(e1 / den, h, m, l);
    P0[base + 256 + tid] = h; P1[base + 256 + tid] = m; P2[base + 256 + tid] = l;
}

// ---------------------------------------------------------------------------
// FAST fused attention (R4 body; used for the H=8 head-split attention only).
// Q f32 (split on the fly), K planes [Mc][768], V planes transposed [768][Mc].
// 2-deep pipelined K loads.  XCD swizzle.  grid: (SS/16, chB*H), block 256.
// O may alias Q (per-block row ownership).
// ---------------------------------------------------------------------------
__global__ __launch_bounds__(256) void attn_fast_k(
    const float* __restrict__ Q,
    const USH* __restrict__ KH, const USH* __restrict__ KM, const USH* __restrict__ KL,
    const USH* __restrict__ VH, const USH* __restrict__ VM, const USH* __restrict__ VL,
    float* __restrict__ O, int H, int hd, int Mc)
{
    __shared__ __align__(16) float S[16][520];      // scores; later P0|P1 overlay
    __shared__ __align__(16) USH P2buf[16 * 520];   // P lo plane
    __shared__ float red[16][16];
    __shared__ float stat[16];

    const int tid  = threadIdx.x;
    const int lane = tid & 63;
    const int w    = tid >> 6;
    const int quad = lane >> 4, l15 = lane & 15;

    const int nbx = gridDim.x;                      // SS/16 = 32
    const int tot = nbx * (int)gridDim.y;
    int bid = blockIdx.y * nbx + blockIdx.x;
    if ((tot & 7) == 0) bid = (bid & 7) * (tot >> 3) + (bid >> 3);
    const int yy = bid / nbx;
    const int q0 = (bid - yy * nbx) * 16;
    const int b = yy / H;
    const int h = yy - b * H;

    const floatx4 zero = {0.f, 0.f, 0.f, 0.f};

    // ---- phase 1: scores.  wave w covers keys [w*128, w*128+128) ----
    floatx4 acc[8];
#pragma unroll
    for (int t = 0; t < 8; ++t) acc[t] = zero;

    const size_t qbase  = ((size_t)(b * SS + q0 + l15)) * DD + h * hd;
    const size_t kstrip = ((size_t)(b * SS + w * 128 + l15)) * DD + h * hd;
    const int nks = hd >> 5;
    for (int ks = 0; ks < nks; ++ks) {
        const int co = ks * 32 + quad * 8;
        float qv[8];
        *(float4*)&qv[0] = *(const float4*)(Q + qbase + co);
        *(float4*)&qv[4] = *(const float4*)(Q + qbase + co + 4);
        short8 qh, qm, ql;
        split3x8(qv, qh, qm, ql);

        size_t ka = kstrip + co;
        short8 khc = *(const short8*)&KH[ka];
        short8 kmc = *(const short8*)&KM[ka];
        short8 klc = *(const short8*)&KL[ka];
#pragma unroll
        for (int t = 0; t < 8; ++t) {
            short8 khn = khc, kmn = kmc, kln = klc;
            if (t < 7) {
                const size_t kb = ka + (size_t)(t + 1) * 16 * DD;
                khn = *(const short8*)&KH[kb];
                kmn = *(const short8*)&KM[kb];
                kln = *(const short8*)&KL[kb];
            }
            acc[t] = MFMA16(qh, khc, acc[t]);
            acc[t] = MFMA16(qh, kmc, acc[t]);
            acc[t] = MFMA16(qm, khc, acc[t]);
            acc[t] = MFMA16(qh, klc, acc[t]);
            acc[t] = MFMA16(ql, khc, acc[t]);
            acc[t] = MFMA16(qm, kmc, acc[t]);
            __builtin_amdgcn_sched_barrier(0);   // keep pipeline 2-deep (no hoist)
            khc = khn; kmc = kmn; klc = kln;
        }
    }
#pragma unroll
    for (int t = 0; t < 8; ++t)
#pragma unroll
        for (int r = 0; r < 4; ++r)
            S[quad * 4 + r][w * 128 + t * 16 + l15] = acc[t][r] * 8.0f;
    __syncthreads();

    // ---- phase 2: softmax (16 threads per row, 32 cols each) ----
    const int row = tid >> 4, c16 = tid & 15;
    const int cb = c16 * 32;
    float mx = -3.4e38f;
#pragma unroll 8
    for (int c = 0; c < 32; ++c) mx = fmaxf(mx, S[row][cb + c]);
    red[row][c16] = mx;
    __syncthreads();
    if (c16 == 0) {
        float m2 = red[row][0];
#pragma unroll
        for (int j = 1; j < 16; ++j) m2 = fmaxf(m2, red[row][j]);
        stat[row] = m2;
    }
    __syncthreads();
    mx = stat[row];
    float ev[32];
    float sum = 0.f;
#pragma unroll 8
    for (int c = 0; c < 32; ++c) {
        ev[c] = expf(S[row][cb + c] - mx);
        sum += ev[c];
    }
    red[row][c16] = sum;
    __syncthreads();
    if (c16 == 0) {
        float s2 = 0.f;
#pragma unroll
        for (int j = 0; j < 16; ++j) s2 += red[row][j];
        stat[row] = s2;
    }
    __syncthreads();                       // all S reads done -> overlay P
    const float den = stat[row];
    USH* const P0 = (USH*)&S[0][0];        // P hi plane
    USH* const P1 = P0 + 16 * 520;         // P mid plane
    USH* const P2 = P2buf;                 // P lo plane
#pragma unroll 8
    for (int c = 0; c < 32; ++c) {
        const float pr = ev[c] / den;      // divide, like numpy softmax
        USH hh, mm, ll;
        split3(pr, hh, mm, ll);
        P0[row * 520 + cb + c] = hh;
        P1[row * 520 + cb + c] = mm;
        P2[row * 520 + cb + c] = ll;
    }
    __syncthreads();

    // ---- phase 3: O = P V.  wave w covers n-tiles nt = w, w+4, ... ----
    const int nnt = hd >> 4;
    for (int nt = w; nt < nnt; nt += 4) {
        floatx4 o = zero;
        const int colg = h * hd + nt * 16 + l15;
        const size_t vb = (size_t)colg * Mc + b * SS;
#pragma unroll 2
        for (int ks = 0; ks < 16; ++ks) {
            const int ko = ks * 32 + quad * 8;
            const short8 ph = *(const short8*)&P0[l15 * 520 + ko];
            const short8 pm = *(const short8*)&P1[l15 * 520 + ko];
            const short8 pl = *(const short8*)&P2[l15 * 520 + ko];
            const short8 vh = *(const short8*)&VH[vb + ko];
            const short8 vm = *(const short8*)&VM[vb + ko];
            const short8 vl = *(const short8*)&VL[vb + ko];
            o = MFMA16(ph, vh, o);
            o = MFMA16(ph, vm, o);
            o = MFMA16(pm, vh, o);
            o = MFMA16(ph, vl, o);
            o = MFMA16(pl, vh, o);
            o = MFMA16(pm, vm, o);
        }
#pragma unroll
        for (int r = 0; r < 4; ++r) {
            const int orow = b * SS + q0 + quad * 4 + r;
            O[(size_t)orow * 768 + colg] = o[r];
        }
    }
}

// ---------------------------------------------------------------------------
// SLOW (R0) fused attention: Q,K f32 row-major; V f32 transposed [768][Mc].
// ---------------------------------------------------------------------------
__global__ __launch_bounds__(256) void attn_k(
    const float* __restrict__ Q, const float* __restrict__ Kp,
    const float* __restrict__ Vt, float* __restrict__ O,
    int H, int hd, int Mc)
{
    __shared__ __align__(16) float S[16][520];
    __shared__ __align__(16) USH P2buf[16 * 520];
    __shared__ float red[16][16];
    __shared__ float stat[16];

    const int tid  = threadIdx.x;
    const int lane = tid & 63;
    const int w    = tid >> 6;
    const int quad = lane >> 4, l15 = lane & 15;
    const int b = blockIdx.y / H;
    const int h = blockIdx.y - b * H;
    const int q0 = blockIdx.x * 16;

    const floatx4 zero = {0.f, 0.f, 0.f, 0.f};

    floatx4 acc[8];
#pragma unroll
    for (int t = 0; t < 8; ++t) acc[t] = zero;

    const size_t qbase = ((size_t)(b * SS + q0 + l15)) * DD + h * hd;
    const int nks = hd >> 5;
    for (int ks = 0; ks < nks; ++ks) {
        const int co = ks * 32 + quad * 8;
        float qv[8];
        *(float4*)&qv[0] = *(const float4*)(Q + qbase + co);
        *(float4*)&qv[4] = *(const float4*)(Q + qbase + co + 4);
        short8 qh, qm, ql;
        split3x8(qv, qh, qm, ql);
#pragma unroll
        for (int t = 0; t < 8; ++t) {
            const size_t kb = ((size_t)(b * SS + w * 128 + t * 16 + l15)) * DD + h * hd + co;
            float kv[8];
            *(float4*)&kv[0] = *(const float4*)(Kp + kb);
            *(float4*)&kv[4] = *(const float4*)(Kp + kb + 4);
            short8 kh, km, kl;
            split3x8(kv, kh, km, kl);
            acc[t] = MFMA16(qh, kh, acc[t]);
            acc[t] = MFMA16(qh, km, acc[t]);
            acc[t] = MFMA16(qm, kh, acc[t]);
            acc[t] = MFMA16(qh, kl, acc[t]);
            acc[t] = MFMA16(ql, kh, acc[t]);
            acc[t] = MFMA16(qm, km, acc[t]);
        }
    }
#pragma unroll
    for (int t = 0; t < 8; ++t)
#pragma unroll
        for (int r = 0; r < 4; ++r)
            S[quad * 4 + r][w * 128 + t * 16 + l15] = acc[t][r] * 8.0f;
    __syncthreads();

    const int row = tid >> 4, c16 = tid & 15;
    const int cb = c16 * 32;
    float mx = -3.4e38f;
#pragma unroll 8
    for (int c = 0; c < 32; ++c) mx = fmaxf(mx, S[row][cb + c]);
    red[row][c16] = mx;
    __syncthreads();
    if (c16 == 0) {
        float m2 = red[row][0];
#pragma unroll
        for (int j = 1; j < 16; ++j) m2 = fmaxf(m2, red[row][j]);
        stat[row] = m2;
    }
    __syncthreads();
    mx = stat[row];
    float ev[32];
    float sum = 0.f;
#pragma unroll 8
    for (int c = 0; c < 32; ++c) {
        ev[c] = expf(S[row][cb + c] - mx);
        sum += ev[c];
    }
    red[row][c16] = sum;
    __syncthreads();
    if (c16 == 0) {
        float s2 = 0.f;
#pragma unroll
        for (int j = 0; j < 16; ++j) s2 += red[row][j];
        stat[row] = s2;
    }
    __syncthreads();
    const float den = stat[row];
    USH* const P0 = (USH*)&S[0][0];
    USH* const P1 = P0 + 16 * 520;
    USH* const P2 = P2buf;
#pragma unroll 8
    for (int c = 0; c < 32; ++c) {
        const float pr = ev[c] / den;
        USH hh, mm, ll;
        split3(pr, hh, mm, ll);
        P0[row * 520 + cb + c] = hh;
        P1[row * 520 + cb + c] = mm;
        P2[row * 520 + cb + c] = ll;
    }
    __syncthreads();

    const int nnt = hd >> 4;
    for (int nt = w; nt < nnt; nt += 4) {
        floatx4 o = zero;
        const int colg = h * hd + nt * 16 + l15;
        const size_t vb = (size_t)colg * Mc + b * SS;
        for (int ks = 0; ks < 16; ++ks) {
            const int ko = ks * 32 + quad * 8;
            const short8 ph = *(const short8*)&P0[l15 * 520 + ko];
            const short8 pm = *(const short8*)&P1[l15 * 520 + ko];
            const short8 pl = *(const short8*)&P2[l15 * 520 + ko];
            float vv[8];
            *(float4*)&vv[0] = *(const float4*)(Vt + vb + ko);
            *(float4*)&vv[4] = *(const float4*)(Vt + vb + ko + 4);
            short8 vh, vm, vl;
            split3x8(vv, vh, vm, vl);
            o = MFMA16(ph, vh, o);
            o = MFMA16(ph, vm, o);
            o = MFMA16(pm, vh, o);
            o = MFMA16(ph, vl, o);
            o = MFMA16(pl, vh, o);
            o = MFMA16(pm, vm, o);
        }
#pragma unroll
        for (int r = 0; r < 4; ++r) {
            const int orow = b * SS + q0 + quad * 4 + r;
            O[(size_t)orow * 768 + colg] = o[r];
        }
    }
}

// ---------------------------------------------------------------------------
// Gate: x = x * softmax(x, row) + x, in-place f32. 1 block / row.
// ---------------------------------------------------------------------------
__global__ __launch_bounds__(256) void gate_k(float* __restrict__ X) {
    __shared__ float red[256];
    const int r = blockIdx.x, tid = threadIdx.x;
    const size_t base = (size_t)r * DD;
    float x[3];
#pragma unroll
    for (int j = 0; j < 3; ++j) x[j] = X[base + tid + j * 256];
    float mx = fmaxf(x[0], fmaxf(x[1], x[2]));
    red[tid] = mx;
    __syncthreads();
    for (int s = 128; s > 0; s >>= 1) {
        if (tid < s) red[tid] = fmaxf(red[tid], red[tid + s]);
        __syncthreads();
    }
    mx = red[0];
    __syncthreads();
    float e[3];
    float sum = 0.f;
#pragma unroll
    for (int j = 0; j < 3; ++j) { e[j] = expf(x[j] - mx); sum += e[j]; }
    red[tid] = sum;
    __syncthreads();
    for (int s = 128; s > 0; s >>= 1) {
        if (tid < s) red[tid] += red[tid + s];
        __syncthreads();
    }
    const float den = red[0];
#pragma unroll
    for (int j = 0; j < 3; ++j)
        X[base + tid + j * 256] = x[j] * (e[j] / den) + x[j];
}

// ---------------------------------------------------------------------------
// Final: es = text + F1 + F2 + F3 ;  out = es * softmax(es,row) + es  (f32)
// ---------------------------------------------------------------------------
__global__ __launch_bounds__(256) void final_k(
    const float* __restrict__ text,
    const float* __restrict__ F1, const float* __restrict__ F2,
    const float* __restrict__ F3, float* __restrict__ out)
{
    __shared__ float red[256];
    const int r = blockIdx.x, tid = threadIdx.x;
    const size_t base = (size_t)r * DD;
    float x[3];
#pragma unroll
    for (int j = 0; j < 3; ++j) {
        const int c = tid + j * 256;
        x[j] = ((text[base + c] + F1[base + c]) + F2[base + c]) + F3[base + c];
    }
    float mx = fmaxf(x[0], fmaxf(x[1], x[2]));
    red[tid] = mx;
    __syncthreads();
    for (int s = 128; s > 0; s >>= 1) {
        if (tid < s) red[tid] = fmaxf(red[tid], red[tid + s]);
        __syncthreads();
    }
    mx = red[0];
    __syncthreads();
    float e[3];
    float sum = 0.f;
#pragma unroll
    for (int j = 0; j < 3; ++j) { e[j] = expf(x[j] - mx); sum += e[j]; }
    red[tid] = sum;
    __syncthreads();
    for (int s = 128; s > 0; s >>= 1) {
        if (tid < s) red[tid] += red[tid + s];
        __syncthreads();
    }
    const float den = red[0];
#pragma unroll
    for (int j = 0; j < 3; ++j) {
        const int c = tid + j * 256;
        out[base + c] = x[j] * (e[j] / den) + x[j];
    }
}

// ===========================================================================
// Host orchestration — dual path.
// ===========================================================================
extern "C" void kernel_launch(void* const* d_in, const int* in_sizes, int n_in,
                              void* d_out, int out_size, void* d_ws, size_t ws_size,
                              hipStream_t stream)
{
    (void)in_sizes; (void)n_in; (void)out_size;

    const float* text    = (const float*)d_in[0];
    const int*   vis_ids = (const int*)d_in[1];
    const int*   ac_ids  = (const int*)d_in[2];
    const float* vis_tab = (const float*)d_in[3];
    const float* ac_tab  = (const float*)d_in[4];
    const float* hv_wq = (const float*)d_in[5],  *hv_bq = (const float*)d_in[6];
    const float* hv_wk = (const float*)d_in[7],  *hv_bk = (const float*)d_in[8];
    const float* hv_wv = (const float*)d_in[9],  *hv_bv = (const float*)d_in[10];
    const float* ha_wq = (const float*)d_in[11], *ha_bq = (const float*)d_in[12];
    const float* ha_wk = (const float*)d_in[13], *ha_bk = (const float*)d_in[14];
    const float* ha_wv = (const float*)d_in[15], *ha_bv = (const float*)d_in[16];
    const float* ht_wq = (const float*)d_in[17], *ht_bq = (const float*)d_in[18];
    const float* ht_wk = (const float*)d_in[19], *ht_bk = (const float*)d_in[20];
    const float* ht_wv = (const float*)d_in[21], *ht_bv = (const float*)d_in[22];
    const float* ht_fcw = (const float*)d_in[23], *ht_fcb = (const float*)d_in[24];
    const float* ffn_w1 = (const float*)d_in[25], *ffn_b1 = (const float*)d_in[26];
    const float* ffn_w2 = (const float*)d_in[27], *ffn_b2 = (const float*)d_in[28];
    const float* cat_w  = (const float*)d_in[29], *cat_b  = (const float*)d_in[30];

    // ---------------- workspace sizing ----------------
    // ws in [227.3MB (R2 fast fit proven), 276MB).  fast@8192 = 227.3MB.
    const size_t SQ   = (size_t)768 * 768;                     // USH per plane
    const size_t WUSH = 3 * (12 * SQ + (size_t)768 * 1536);    // 24,772,608 USH
    const size_t TABF = (size_t)512 * 384 * 2;                 // floats
    int Mc = 0, fast = 0;
    for (int cand = MM; cand >= 512; cand >>= 1) {
        const size_t nf = WUSH * sizeof(USH) + TABF * 4 + (size_t)cand * 768 * 28;
        const size_t ns = WUSH * sizeof(USH) + (size_t)cand * 768 * 24;
        if (nf <= ws_size) { Mc = cand; fast = 1; break; }
        if (ns <= ws_size) { Mc = cand; fast = 0; break; }
    }
    if (Mc == 0) return;    // diagnostic: wrong output, not a fault
    const int nchunk = MM / Mc;
    const int chB    = Mc / SS;

    USH* p = (USH*)d_ws;
    USH *wt0[13], *wt1[13], *wt2[13];
    for (int i = 0; i < 13; ++i) {
        const size_t sz = (i == 12) ? (size_t)768 * 1536 : SQ;
        wt0[i] = p; p += sz;
        wt1[i] = p; p += sz;
        wt2[i] = p; p += sz;
    }

    // weight indices: 0 hv_wq 1 hv_wk 2 hv_wv 3 ha_wq 4 ha_wk 5 ha_wv
    //                 6 ht_wq 7 ht_wk 8 ht_wv 9 ht_fcw 10 ffn_w1 11 ffn_w2 12 cat_w
    TransArgs ta;
    const float* tin[13] = {hv_wq, hv_wk, hv_wv, ha_wq, ha_wk, ha_wv,
                            ht_wq, ht_wk, ht_wv, ht_fcw, ffn_w1, ffn_w2, cat_w};
    for (int i = 0; i < 13; ++i) {
        ta.in[i] = tin[i]; ta.o0[i] = wt0[i]; ta.o1[i] = wt1[i]; ta.o2[i] = wt2[i];
        ta.R[i] = (i == 12) ? 1536 : 768;
    }
    trans_k<<<dim3(48, 24, 13), 256, 0, stream>>>(ta);

    const size_t PSZ = (size_t)Mc * 768;       // elements per plane
    const dim3 gg(Mc / 128, DD / 128), gb(256);
    const int ropeg = Mc * 384 / 256;
    const float* NULF = nullptr;
    USH* const NUSH = nullptr;

    if (fast) {
        // layout: weights | tab | A,B,C,F f32 | KH KM KL VH VM VL bf16
        float* tab = (float*)p;
        float* fp  = tab + TABF;
        float *A_ = fp + 0 * PSZ, *B_ = fp + 1 * PSZ;
        float *C_ = fp + 2 * PSZ, *F_ = fp + 3 * PSZ;
        USH* KH = (USH*)(fp + 4 * PSZ);
        USH* KM = KH + PSZ;  USH* KL = KM + PSZ;
        USH* VH = KL + PSZ;  USH* VM = VH + PSZ;  USH* VL = VM + PSZ;

        tab_k<<<(512 * 384) / 256, 256, 0, stream>>>(tab);

// plain GEMM (f32 out)
#define GE(A0P, A1P, WI, LDB, BIAS, CP, KK, ACT) \
    gemm_k<<<gg, gb, 0, stream>>>(A0P, A1P, NUSH, NUSH, NUSH, 768, \
        wt0[WI], wt1[WI], wt2[WI], LDB, (size_t)0, BIAS, 1.0f, CP, 768, \
        NUSH, NUSH, NUSH, tab, KK, ACT, 0, 0, Mc)
// Q GEMM: rope fused, f32 out
#define GQ(A0P, WI, BIAS, CP) \
    gemm_k<<<gg, gb, 0, stream>>>(A0P, NULF, NUSH, NUSH, NUSH, 768, \
        wt0[WI], wt1[WI], wt2[WI], 768, (size_t)0, BIAS, 1.0f, CP, 768, \
        NUSH, NUSH, NUSH, tab, 768, 0, 0, 1, Mc)
// K GEMM: rope fused, row-major 3-plane bf16 out
#define GK(A0P, WI, BIAS) \
    gemm_k<<<gg, gb, 0, stream>>>(A0P, NULF, NUSH, NUSH, NUSH, 768, \
        wt0[WI], wt1[WI], wt2[WI], 768, (size_t)0, BIAS, 1.0f, (float*)nullptr, 768, \
        KH, KM, KL, tab, 768, 0, 3, 1, Mc)
// V GEMM: transposed 3-plane bf16 out (LDS-coalesced epilogue)
#define GV(A0P, WI, BIAS) \
    gemm_k<<<gg, gb, 0, stream>>>(A0P, NULF, NUSH, NUSH, NUSH, 768, \
        wt0[WI], wt1[WI], wt2[WI], 768, (size_t)0, BIAS, 1.0f, (float*)nullptr, 768, \
        VH, VM, VL, tab, 768, 0, 1, 0, Mc)
// score GEMM: S = (Q @ K[b]^T)*8 -> outc [Mc][512]
#define SGEMM(QP) \
    gemm_k<<<dim3(Mc / 128, 4), gb, 0, stream>>>(QP, NULF, NUSH, NUSH, NUSH, 768, \
        KH, KM, KL, 768, (size_t)512 * 768, NULF, 8.0f, outc, 512, \
        NUSH, NUSH, NUSH, tab, 768, 0, 0, 0, Mc)
// row softmax -> P planes overwrite dead K planes (stride 512)
#define SMAX() smax_k<<<Mc, 256, 0, stream>>>(outc, KH, KM, KL)
// PV GEMM: O = P @ V[b] -> f32 [Mc][768]
#define PVG(OP) \
    gemm_k<<<dim3(Mc / 128, 6), gb, 0, stream>>>(NULF, NULF, KH, KM, KL, 512, \
        VH, VM, VL, Mc, (size_t)512, NULF, 1.0f, OP, 768, \
        NUSH, NUSH, NUSH, tab, 512, 0, 0, 0, Mc)
#define ATTNF(QP, OP, HH, HD) \
    attn_fast_k<<<dim3(SS / 16, chB * (HH)), 256, 0, stream>>>(QP, KH, KM, KL, \
                                                  VH, VM, VL, OP, HH, HD, Mc)
#define GATE(XP) gate_k<<<Mc, 256, 0, stream>>>(XP)

        for (int c = 0; c < nchunk; ++c) {
            const float* tx = text + (size_t)c * PSZ;
            const int* vi = vis_ids + (size_t)c * Mc;
            const int* ai = ac_ids  + (size_t)c * Mc;
            float* outc = (float*)d_out + (size_t)c * PSZ;   // scratch till final

            gather_k<<<Mc * 192 / 256, 256, 0, stream>>>(vi, vis_tab, A_);  // Ev
            gather_k<<<Mc * 192 / 256, 256, 0, stream>>>(ai, ac_tab, B_);   // Ea

            // ---- v1 = hv(text, Ev) -> F_ ----
            GQ(tx, 0, hv_bq, C_);
            GK(A_, 1, hv_bk);  GV(A_, 2, hv_bv);
            SGEMM(C_); SMAX(); PVG(F_);                      // (Ev dead)

            // ---- a1 = ha(text, Ea) -> A_ ----
            GQ(tx, 3, ha_bq, C_);
            GK(B_, 4, ha_bk);  GV(B_, 5, ha_bv);
            SGEMM(C_); SMAX(); PVG(A_);                      // (Ea dead)

            // ---- v2 = hv(v1, a1) -> C_ ----
            GQ(F_, 0, hv_bq, C_);
            GK(A_, 1, hv_bk);  GV(A_, 2, hv_bv);
            SGEMM(C_); SMAX(); PVG(C_);                      // C_ (Q) dead after SGEMM

            // ---- a2 = ha(a1, v1) -> B_ ----
            GQ(A_, 3, ha_bq, B_);
            GK(F_, 4, ha_bk);  GV(F_, 5, ha_bv);
            SGEMM(B_); SMAX(); PVG(B_);                      // B_ (Q) dead after SGEMM

            // ---- F1 = ffn(gate(cat(v1,a1) @ cat_w)) -> A_ ----
            GE(F_, A_, 12, 1536, cat_b, outc, 1536, 0);      // T1
            GATE(outc);
            GE(outc, NULF, 10, 768, ffn_b1, F_, 768, 1);     // H (v1 dead)
            GE(F_, NULF, 11, 768, ffn_b2, A_, 768, 0);       // F1 -> A_ (a1 dead)

            // ---- F2 = ffn(gate(cat(v2,a2) @ cat_w)) -> C_ ----
            GE(C_, B_, 12, 1536, cat_b, outc, 1536, 0);      // T2
            GATE(outc);
            GE(outc, NULF, 10, 768, ffn_b1, F_, 768, 1);     // H
            GE(F_, NULF, 11, 768, ffn_b2, C_, 768, 0);       // F2 -> C_ (v2 dead)

            // ---- F3 = ffn(gate(fc(ht(F1, text)))) -> F_ ----
            GQ(A_, 6, ht_bq, B_);                            // Q <- F1 (a2 dead)
            GK(tx, 7, ht_bk);  GV(tx, 8, ht_bv);
            ATTNF(B_, B_, 8, 96);                            // AO aliases Q
            GE(B_, NULF, 9, 768, ht_fcb, F_, 768, 0);        // fc
            GATE(F_);
            GE(F_, NULF, 10, 768, ffn_b1, B_, 768, 1);       // H
            GE(B_, NULF, 11, 768, ffn_b2, F_, 768, 0);       // F3

            final_k<<<Mc, 256, 0, stream>>>(tx, A_, C_, F_, outc);
        }
#undef GE
#undef GQ
#undef GK
#undef GV
#undef SGEMM
#undef SMAX
#undef PVG
#undef ATTNF
#undef GATE
    } else {
        // -------- SLOW path: exact R0 (6 f32 planes, on-the-fly splits) ------
        float* fp = (float*)p;
        float *A_ = fp + 0 * PSZ, *B_ = fp + 1 * PSZ, *C_ = fp + 2 * PSZ;
        float *D_ = fp + 3 * PSZ, *E_ = fp + 4 * PSZ, *F_ = fp + 5 * PSZ;

#define GEMM(A0P, A1P, WI, LDB, BIAS, CP, KK, ACT, TOUT) \
    gemm_k<<<gg, gb, 0, stream>>>(A0P, A1P, NUSH, NUSH, NUSH, 768, \
        wt0[WI], wt1[WI], wt2[WI], LDB, (size_t)0, BIAS, 1.0f, CP, 768, \
        NUSH, NUSH, NUSH, NULF, KK, ACT, TOUT, 0, Mc)
#define ROPE(XP) rope_k<<<ropeg, 256, 0, stream>>>(XP)
#define ATTN(QP, KP, VP, OP, HH, HD) \
    attn_k<<<dim3(SS / 16, chB * (HH)), 256, 0, stream>>>(QP, KP, VP, OP, HH, HD, Mc)
#define GATE(XP) gate_k<<<Mc, 256, 0, stream>>>(XP)

        for (int c = 0; c < nchunk; ++c) {
            const float* tx = text + (size_t)c * PSZ;
            const int* vi = vis_ids + (size_t)c * Mc;
            const int* ai = ac_ids  + (size_t)c * Mc;
            float* outc = (float*)d_out + (size_t)c * PSZ;

            gather_k<<<Mc * 192 / 256, 256, 0, stream>>>(vi, vis_tab, A_);
            gather_k<<<Mc * 192 / 256, 256, 0, stream>>>(ai, ac_tab, B_);

            GEMM(tx, NULF, 0, 768, hv_bq, C_, 768, 0, 0);
            GEMM(A_, NULF, 1, 768, hv_bk, D_, 768, 0, 0);
            GEMM(A_, NULF, 2, 768, hv_bv, E_, 768, 0, 2);
            ROPE(C_); ROPE(D_);
            ATTN(C_, D_, E_, F_, 1, 768);

            GEMM(tx, NULF, 3, 768, ha_bq, C_, 768, 0, 0);
            GEMM(B_, NULF, 4, 768, ha_bk, D_, 768, 0, 0);
            GEMM(B_, NULF, 5, 768, ha_bv, E_, 768, 0, 2);
            ROPE(C_); ROPE(D_);
            ATTN(C_, D_, E_, A_, 1, 768);

            GEMM(F_, NULF, 0, 768, hv_bq, C_, 768, 0, 0);
            GEMM(A_, NULF, 1, 768, hv_bk, D_, 768, 0, 0);
            GEMM(A_, NULF, 2, 768, hv_bv, E_, 768, 0, 2);
            ROPE(C_); ROPE(D_);
            ATTN(C_, D_, E_, C_, 1, 768);

            GEMM(A_, NULF, 3, 768, ha_bq, B_, 768, 0, 0);
            GEMM(F_, NULF, 4, 768, ha_bk, D_, 768, 0, 0);
            GEMM(F_, NULF, 5, 768, ha_bv, E_, 768, 0, 2);
            ROPE(B_); ROPE(D_);
            ATTN(B_, D_, E_, B_, 1, 768);

            GEMM(F_, A_, 12, 1536, cat_b, D_, 1536, 0, 0);
            GATE(D_);
            GEMM(D_, NULF, 10, 768, ffn_b1, E_, 768, 1, 0);
            GEMM(E_, NULF, 11, 768, ffn_b2, F_, 768, 0, 0);

            GEMM(C_, B_, 12, 1536, cat_b, A_, 1536, 0, 0);
            GATE(A_);
            GEMM(A_, NULF, 10, 768, ffn_b1, C_, 768, 1, 0);
            GEMM(C_, NULF, 11, 768, ffn_b2, B_, 768, 0, 0);

            GEMM(F_, NULF, 6, 768, ht_bq, C_, 768, 0, 0);
            GEMM(tx, NULF, 7, 768, ht_bk, D_, 768, 0, 0);
            GEMM(tx, NULF, 8, 768, ht_bv, E_, 768, 0, 2);
            ROPE(C_); ROPE(D_);
            ATTN(C_, D_, E_, C_, 8, 96);
            GEMM(C_, NULF, 9, 768, ht_fcb, A_, 768, 0, 0);
            GATE(A_);
            GEMM(A_, NULF, 10, 768, ffn_b1, C_, 768, 1, 0);
            GEMM(C_, NULF, 11, 768, ffn_b2, D_, 768, 0, 0);

            final_k<<<Mc, 256, 0, stream>>>(tx, F_, B_, D_, outc);
        }
#undef GEMM
#undef ROPE
#undef ATTN
#undef GATE
    }
}